// Round 4
// baseline (479.550 us; speedup 1.0000x reference)
//
#include <hip/hip_runtime.h>

typedef unsigned short u16;
typedef unsigned int u32;
typedef float f32x4v __attribute__((ext_vector_type(4)));
typedef __bf16 bf16x8 __attribute__((ext_vector_type(8)));

#define GAS __attribute__((address_space(1)))
#define LAS __attribute__((address_space(3)))

__device__ __forceinline__ u16 f2bf(float f) {
  u32 u = __builtin_bit_cast(u32, f);
  u32 r = (u + 0x7FFFu + ((u >> 16) & 1u)) >> 16;  // RNE
  return (u16)r;
}
__device__ __forceinline__ float bf2f(u16 h) {
  return __builtin_bit_cast(float, (u32)h << 16);
}
__device__ __forceinline__ void gld_lds16(const void* g, void* l) {
  __builtin_amdgcn_global_load_lds((const GAS void*)g, (LAS void*)l, 16, 0, 0);
}

// ---------------------------------------------------------------------------
// 256x256 MFMA GEMM, BK=32, 512 thr / 8 waves, per-wave 128x64 output.
// 2-phase schedule: stage(next) -> ds_read+MFMA(cur) -> one __syncthreads.
// LDS: 2 dbuf x [256][32] bf16 per operand = 64 KB static.
//   C[m][n] = sum_k A[m][k] * B[n][k]; fp32 partial at Cp + z*strC.
// CONV=1: B is a zero-padded channel-last image stack [nImg][900][Cin]
//   (30x30 frame, interior 28x28); B-"rows" are pixels; K = 9*Cin tap-major.
// z = zb*S + s selects batch zb and K-chunk s (k in [s*Kc, (s+1)*Kc)).
// ---------------------------------------------------------------------------
template <int CONV>
__global__ __launch_bounds__(512) void gemm256(
    const u16* __restrict__ A, const u16* __restrict__ B, float* __restrict__ Cp,
    int M, int N, int Kc, int fullK, int S,
    long strA, long strB, long strC, int Cin)
{
  __shared__ u16 sA[2][256 * 32];
  __shared__ u16 sB[2][256 * 32];
  const int t = threadIdx.x, lane = t & 63, wave = t >> 6;
  const int z = blockIdx.z, zb = z / S, s = z - zb * S;
  const int m0 = blockIdx.x * 256, n0 = blockIdx.y * 256;
  const int kbeg = s * Kc;

  // staging map: issue q in {0,1}: row = q*128 + (t>>2), 16B-chunk = t&3.
  // LDS dest (linear, wave-uniform + lane*16B): q*8192B + wave*1024B + lane*16B.
  const u16* Ap[2]; const u16* Bp[2];
  #pragma unroll
  for (int q = 0; q < 2; ++q) {
    int ra = m0 + q * 128 + (t >> 2); if (ra >= M) ra = M - 1;
    Ap[q] = A + (long)zb * strA + (long)ra * fullK + (t & 3) * 8;
    if constexpr (CONV) {
      int pn = n0 + q * 128 + (t >> 2); if (pn >= N) pn = 0;
      const int img = pn / 784, p = pn - img * 784;
      const int py = p / 28, px = p - py * 28;
      Bp[q] = B + ((long)img * 900 + (py + 1) * 30 + (px + 1)) * Cin + (t & 3) * 8;
    } else {
      int rb = n0 + q * 128 + (t >> 2); if (rb >= N) rb = N - 1;
      Bp[q] = B + (long)zb * strB + (long)rb * fullK + (t & 3) * 8;
    }
  }
  const int ldst = wave * 512 + lane * 8;  // u16 units

  auto stage = [&](int buf, int kg) {
    long boff;
    if constexpr (CONV) {
      const int tap = kg / Cin, kc = kg - tap * Cin;
      boff = (long)((tap / 3 - 1) * 30 + (tap % 3 - 1)) * Cin + kc;
    } else {
      boff = kg;
    }
    #pragma unroll
    for (int q = 0; q < 2; ++q) {
      gld_lds16(Ap[q] + kg,   &sA[buf][q * 4096 + ldst]);
      gld_lds16(Bp[q] + boff, &sB[buf][q * 4096 + ldst]);
    }
  };

  const int wrow = (wave & 1) * 128, wcol = (wave >> 1) * 64;
  const int lr = lane & 15, hi = lane >> 4;
  f32x4v acc[8][4] = {};
  const int niter = Kc >> 5;

  stage(0, kbeg);
  __syncthreads();
  for (int it = 0; it < niter; ++it) {
    const int cur = it & 1;
    if (it + 1 < niter) stage(cur ^ 1, kbeg + (it + 1) * 32);
    bf16x8 af[8], bf[4];
    #pragma unroll
    for (int m = 0; m < 8; ++m) af[m] = *(const bf16x8*)&sA[cur][(wrow + m*16 + lr) * 32 + hi * 8];
    #pragma unroll
    for (int n = 0; n < 4; ++n) bf[n] = *(const bf16x8*)&sB[cur][(wcol + n*16 + lr) * 32 + hi * 8];
    #pragma unroll
    for (int m = 0; m < 8; ++m)
      #pragma unroll
      for (int n = 0; n < 4; ++n)
        acc[m][n] = __builtin_amdgcn_mfma_f32_16x16x32_bf16(af[m], bf[n], acc[m][n], 0, 0, 0);
    __syncthreads();
  }

  // D: lane l reg r -> row=(l>>4)*4+r, col=l&15
  float* Co = Cp + (long)z * strC;
  const int lq = hi * 4;
  #pragma unroll
  for (int m = 0; m < 8; ++m)
    #pragma unroll
    for (int r = 0; r < 4; ++r) {
      const int row = m0 + wrow + m * 16 + lq + r;
      if (row >= M) continue;
      #pragma unroll
      for (int n = 0; n < 4; ++n) {
        const int col = n0 + wcol + n * 16 + lr;
        if (col < N) Co[(long)row * N + col] = acc[m][n][r];
      }
    }
}

// ---------------------------------------------------------------------------
// 128x128 glds GEMM (kept for logits). OUT=1: bf16 final, *scale.
// ---------------------------------------------------------------------------
template <int BK, int OUT>
__global__ __launch_bounds__(256) void gemm_glds(
    const u16* __restrict__ A, const u16* __restrict__ B, void* __restrict__ C,
    int M, int N, int Kc, int fullK, int S,
    long strA, long strB, long strC, float scale)
{
  constexpr int CPR = BK / 8;
  constexpr int ISS = BK / 16;
  __shared__ u16 sA[2][128 * BK];
  __shared__ u16 sB[2][128 * BK];
  const int t = threadIdx.x, lane = t & 63, wave = t >> 6;
  const int z = blockIdx.z, zb = z / S, s = z - zb * S;
  const int m0 = blockIdx.x * 128, n0 = blockIdx.y * 128;
  const int kbeg = s * Kc;

  const u16* Aptr[ISS]; const u16* Bptr[ISS]; int lofs[ISS];
  #pragma unroll
  for (int i = 0; i < ISS; ++i) {
    const int tp = i * 256 + t;
    const int r = tp / CPR, c16 = tp % CPR;
    int ra = m0 + r; if (ra >= M) ra = M - 1;
    int rb = n0 + r; if (rb >= N) rb = N - 1;
    Aptr[i] = A + (long)zb * strA + (long)ra * fullK + kbeg + c16 * 8;
    Bptr[i] = B + (long)zb * strB + (long)rb * fullK + kbeg + c16 * 8;
    lofs[i] = (i * 256 + (wave << 6)) * 8;
  }
  auto stage = [&](int buf, int k0) {
    #pragma unroll
    for (int i = 0; i < ISS; ++i) {
      gld_lds16(Aptr[i] + k0, &sA[buf][lofs[i]]);
      gld_lds16(Bptr[i] + k0, &sB[buf][lofs[i]]);
    }
  };

  const int wr = (wave >> 1) * 64, wc = (wave & 1) * 64;
  const int lr = lane & 15, lg = (lane >> 4) * 8;
  f32x4v acc[4][4] = {};
  const int niter = Kc / BK;

  stage(0, 0);
  __syncthreads();
  for (int it = 0; it < niter; ++it) {
    const int cur = it & 1;
    if (it + 1 < niter) stage(cur ^ 1, (it + 1) * BK);
    #pragma unroll
    for (int kk = 0; kk < BK; kk += 32) {
      const int lk = kk + lg;
      bf16x8 af[4], bv[4];
      #pragma unroll
      for (int i = 0; i < 4; ++i) af[i] = *(const bf16x8*)&sA[cur][(wr + i*16 + lr) * BK + lk];
      #pragma unroll
      for (int j = 0; j < 4; ++j) bv[j] = *(const bf16x8*)&sB[cur][(wc + j*16 + lr) * BK + lk];
      #pragma unroll
      for (int i = 0; i < 4; ++i)
        #pragma unroll
        for (int j = 0; j < 4; ++j)
          acc[i][j] = __builtin_amdgcn_mfma_f32_16x16x32_bf16(af[i], bv[j], acc[i][j], 0, 0, 0);
    }
    __syncthreads();
  }

  const int lq = (lane >> 4) * 4;
  if constexpr (OUT == 0) {
    float* Cp = (float*)C + (long)z * strC;
    #pragma unroll
    for (int i = 0; i < 4; ++i)
      #pragma unroll
      for (int r = 0; r < 4; ++r) {
        const int row = m0 + wr + i*16 + lq + r;
        if (row >= M) continue;
        #pragma unroll
        for (int j = 0; j < 4; ++j) {
          const int col = n0 + wc + j*16 + lr;
          if (col < N) Cp[(long)row * N + col] = acc[i][j][r];
        }
      }
  } else {
    u16* Cp = (u16*)C + (long)zb * strC;
    #pragma unroll
    for (int i = 0; i < 4; ++i)
      #pragma unroll
      for (int r = 0; r < 4; ++r) {
        const int row = m0 + wr + i*16 + lq + r;
        if (row >= M) continue;
        #pragma unroll
        for (int j = 0; j < 4; ++j) {
          const int col = n0 + wc + j*16 + lr;
          if (col < N) Cp[(long)row * N + col] = f2bf(acc[i][j][r] * scale);
        }
      }
  }
}

// ---------------------------------------------------------------------------
// 128x128 implicit-conv (kept for conv2: M=64). Padded image B.
// ---------------------------------------------------------------------------
__global__ __launch_bounds__(256) void conv_glds(
    const u16* __restrict__ Wt, const u16* __restrict__ imgP,
    float* __restrict__ Cp, int M, int Cin, int Ntot, int Kc)
{
  __shared__ u16 sA[2][128 * 32];
  __shared__ u16 sB[2][128 * 32];
  const int t = threadIdx.x, lane = t & 63, wave = t >> 6;
  const int z = blockIdx.z;
  const int m0 = blockIdx.x * 128, n0 = blockIdx.y * 128;
  const int kbeg = z * Kc;

  const u16* Aptr[2]; const u16* Bptr[2]; int lofs[2];
  #pragma unroll
  for (int i = 0; i < 2; ++i) {
    const int tp = i * 256 + t;
    const int r = tp >> 2, c16 = tp & 3;
    int ra = m0 + r; if (ra >= M) ra = M - 1;
    int pn = n0 + r; if (pn >= Ntot) pn = 0;
    const int img = pn / 784, p = pn - img * 784;
    const int py = p / 28, px = p - py * 28;
    Aptr[i] = Wt + (long)ra * (9 * Cin) + c16 * 8;
    Bptr[i] = imgP + ((long)img * 900 + (py + 1) * 30 + (px + 1)) * Cin + c16 * 8;
    lofs[i] = (i * 256 + (wave << 6)) * 8;
  }
  auto stage = [&](int buf, int kg) {
    const int tap = kg / Cin, kc = kg - tap * Cin;
    const long off = (long)((tap / 3 - 1) * 30 + (tap % 3 - 1)) * Cin + kc;
    #pragma unroll
    for (int i = 0; i < 2; ++i) {
      gld_lds16(Aptr[i] + kg, &sA[buf][lofs[i]]);
      gld_lds16(Bptr[i] + off, &sB[buf][lofs[i]]);
    }
  };

  const int wr = (wave >> 1) * 64, wc = (wave & 1) * 64;
  const int lr = lane & 15, lk = (lane >> 4) * 8;
  f32x4v acc[4][4] = {};
  const int niter = Kc >> 5;

  stage(0, kbeg);
  __syncthreads();
  for (int it = 0; it < niter; ++it) {
    const int cur = it & 1;
    if (it + 1 < niter) stage(cur ^ 1, kbeg + (it + 1) * 32);
    bf16x8 af[4], bv[4];
    #pragma unroll
    for (int i = 0; i < 4; ++i) af[i] = *(const bf16x8*)&sA[cur][(wr + i*16 + lr) * 32 + lk];
    #pragma unroll
    for (int j = 0; j < 4; ++j) bv[j] = *(const bf16x8*)&sB[cur][(wc + j*16 + lr) * 32 + lk];
    #pragma unroll
    for (int i = 0; i < 4; ++i)
      #pragma unroll
      for (int j = 0; j < 4; ++j)
        acc[i][j] = __builtin_amdgcn_mfma_f32_16x16x32_bf16(af[i], bv[j], acc[i][j], 0, 0, 0);
    __syncthreads();
  }

  float* Co = Cp + (long)z * M * Ntot;
  const int lq = (lane >> 4) * 4;
  #pragma unroll
  for (int i = 0; i < 4; ++i)
    #pragma unroll
    for (int r = 0; r < 4; ++r) {
      const int row = m0 + wr + i*16 + lq + r;
      if (row >= M) continue;
      #pragma unroll
      for (int j = 0; j < 4; ++j) {
        const int col = n0 + wc + j*16 + lr;
        if (col < Ntot) Co[(long)row * Ntot + col] = acc[i][j][r];
      }
    }
}

// ---------------------------------------------------------------------------
// Helpers: transpose fp32->bf16, convert, weight permute, zero-fill
// ---------------------------------------------------------------------------
__global__ __launch_bounds__(256) void transpose_bf(
    const float* __restrict__ in, u16* __restrict__ out,
    int R, int C, long strOutZ, int ldOut, int colOff)
{
  __shared__ float tile[32][33];
  in  += (long)blockIdx.z * R * C;
  out += (long)blockIdx.z * strOutZ;
  const int c0 = blockIdx.x * 32, r0 = blockIdx.y * 32;
  const int tx = threadIdx.x & 31, ty = threadIdx.x >> 5;
  for (int i = ty; i < 32; i += 8) {
    const int r = r0 + i, c = c0 + tx;
    tile[i][tx] = (r < R && c < C) ? in[(long)r * C + c] : 0.0f;
  }
  __syncthreads();
  for (int i = ty; i < 32; i += 8) {
    const int r = r0 + tx, c = c0 + i;
    if (c < C && r < R)
      out[(long)c * ldOut + colOff + r] = f2bf(tile[tx][i]);
  }
}

__global__ __launch_bounds__(256) void convert_bf(
    const float* __restrict__ in, u16* __restrict__ out, long n8)
{
  const long i = (long)blockIdx.x * 256 + threadIdx.x;
  if (i >= n8) return;
  const float4* p = (const float4*)in + i * 2;
  const float4 a = p[0], b = p[1];
  u16 o[8] = {f2bf(a.x), f2bf(a.y), f2bf(a.z), f2bf(a.w),
              f2bf(b.x), f2bf(b.y), f2bf(b.z), f2bf(b.w)};
  ((uint4*)out)[i] = *(uint4*)o;
}

__global__ __launch_bounds__(256) void permute_w(
    const float* __restrict__ src, u16* __restrict__ dst, int M, int Cin)
{
  const long total = (long)M * 9 * Cin;
  const long idx = (long)blockIdx.x * 256 + threadIdx.x;
  if (idx >= total) return;
  const int c = (int)(idx % Cin);
  const int tap = (int)((idx / Cin) % 9);
  const int m = (int)(idx / ((long)9 * Cin));
  dst[idx] = f2bf(src[((long)m * Cin + c) * 9 + tap]);
}

__global__ __launch_bounds__(256) void zfill(u32* __restrict__ p, long n) {
  const long stride = (long)gridDim.x * 256;
  for (long i = (long)blockIdx.x * 256 + threadIdx.x; i < n; i += stride) p[i] = 0;
}

// ---------------------------------------------------------------------------
// Non-transposing reduces (gemm256 outputs are already layout-correct)
// ---------------------------------------------------------------------------
// conv1: parts[S][1568][512] (pixel-major) -> out1P[b][900pad][512] bf16 +b1
__global__ __launch_bounds__(256) void reduce_c1_cl(
    const float* __restrict__ parts, u16* __restrict__ dst,
    const float* __restrict__ bias, int S)
{
  const long idx = (long)blockIdx.x * 256 + threadIdx.x;
  if (idx >= 1568L * 128) return;
  const int c4 = (int)(idx & 127), p = (int)(idx >> 7);
  const int c = c4 * 4;
  f32x4v sum = *(const f32x4v*)&bias[c];
  for (int s = 0; s < S; ++s)
    sum += *(const f32x4v*)&parts[((long)s * 1568 + p) * 512 + c];
  const int im = p / 784, q = p - im * 784;
  const int qpad = (q / 28 + 1) * 30 + (q % 28 + 1);
  u16 o[4] = {f2bf(sum[0]), f2bf(sum[1]), f2bf(sum[2]), f2bf(sum[3])};
  *(uint2*)&dst[((long)im * 900 + qpad) * 512 + c] = *(uint2*)o;
}

// readout: parts[(b*S+s)][784][1536] -> concatP[b*3+n][900pad][768] ch 0..511
__global__ __launch_bounds__(256) void reduce_ro_cl(
    const float* __restrict__ parts, u16* __restrict__ dst, int S)
{
  const long idx = (long)blockIdx.x * 256 + threadIdx.x;
  if (idx >= 2L * 784 * 384) return;
  const int c4 = (int)(idx % 384);
  const long rest = idx / 384;
  const int p = (int)(rest % 784), b = (int)(rest / 784);
  const int c = c4 * 4;
  f32x4v sum = {0, 0, 0, 0};
  for (int s = 0; s < S; ++s)
    sum += *(const f32x4v*)&parts[((long)(b * S + s) * 784 + p) * 1536 + c];
  const int n = c >> 9, cc = c & 511;
  const int qpad = (p / 28 + 1) * 30 + (p % 28 + 1);
  u16 o[4] = {f2bf(sum[0]), f2bf(sum[1]), f2bf(sum[2]), f2bf(sum[3])};
  *(uint2*)&dst[((long)(b * 3 + n) * 900 + qpad) * 768 + cc] = *(uint2*)o;
}

// conv2: parts[S][64][1568] -> qkT[b][784][64] (+b2)   (transposing, small)
__global__ __launch_bounds__(256) void reduceT_qk(
    const float* __restrict__ parts, u16* __restrict__ dst,
    const float* __restrict__ bias, int S)
{
  __shared__ float tile[32][33];
  const int b = blockIdx.z, c0 = blockIdx.x * 32, p0 = blockIdx.y * 32;
  const int tx = threadIdx.x & 31, ty = threadIdx.x >> 5;
  for (int i = ty; i < 32; i += 8) {
    const int pc = min(p0 + tx, 783);
    const long base = (long)(c0 + i) * 1568 + b * 784 + pc;
    float s = 0;
    for (int k = 0; k < S; ++k) s += parts[(long)k * 64 * 1568 + base];
    tile[i][tx] = s;
  }
  __syncthreads();
  for (int i = ty; i < 32; i += 8) {
    const int p = p0 + i, c = c0 + tx;
    if (p < 784)
      dst[((long)b * 784 + p) * 64 + c] = f2bf(tile[tx][i] + bias[c]);
  }
}

// h: hin[img][256][784] -> concatP[img][900pad][ch 512..767]
__global__ __launch_bounds__(256) void transT_h(
    const float* __restrict__ h, u16* __restrict__ dst)
{
  __shared__ float tile[32][33];
  const int zimg = blockIdx.z, c0 = blockIdx.x * 32, p0 = blockIdx.y * 32;
  const int tx = threadIdx.x & 31, ty = threadIdx.x >> 5;
  for (int i = ty; i < 32; i += 8) {
    const int pc = min(p0 + tx, 783);
    tile[i][tx] = h[((long)zimg * 256 + c0 + i) * 784 + pc];
  }
  __syncthreads();
  for (int i = ty; i < 32; i += 8) {
    const int p = p0 + i, c = c0 + tx;
    if (p < 784) {
      const int qpad = (p / 28 + 1) * 30 + (p % 28 + 1);
      dst[((long)zimg * 900 + qpad) * 768 + 512 + c] = f2bf(tile[tx][i]);
    }
  }
}

// ---------------------------------------------------------------------------
// In-place softmax over rows of 12544 bf16 (one block per row)
// ---------------------------------------------------------------------------
__global__ __launch_bounds__(256) void softmax_inplace(u16* __restrict__ buf)
{
  u16* ptr = buf + (long)blockIdx.x * 12544;
  uint4* p4 = (uint4*)ptr;
  const int t = threadIdx.x;
  __shared__ float red[4];
  float mx = -3.0e38f;
  for (int v = t; v < 1568; v += 256) {
    uint4 u = p4[v];
    const u32 w[4] = {u.x, u.y, u.z, u.w};
    #pragma unroll
    for (int q = 0; q < 4; ++q) {
      mx = fmaxf(mx, bf2f((u16)(w[q] & 0xFFFFu)));
      mx = fmaxf(mx, bf2f((u16)(w[q] >> 16)));
    }
  }
  #pragma unroll
  for (int o = 32; o > 0; o >>= 1) mx = fmaxf(mx, __shfl_xor(mx, o));
  if ((t & 63) == 0) red[t >> 6] = mx;
  __syncthreads();
  mx = fmaxf(fmaxf(red[0], red[1]), fmaxf(red[2], red[3]));

  float s = 0.0f;
  for (int v = t; v < 1568; v += 256) {
    uint4 u = p4[v];
    const u32 w[4] = {u.x, u.y, u.z, u.w};
    #pragma unroll
    for (int q = 0; q < 4; ++q) {
      s += __expf(bf2f((u16)(w[q] & 0xFFFFu)) - mx);
      s += __expf(bf2f((u16)(w[q] >> 16)) - mx);
    }
  }
  #pragma unroll
  for (int o = 32; o > 0; o >>= 1) s += __shfl_xor(s, o);
  __syncthreads();
  if ((t & 63) == 0) red[t >> 6] = s;
  __syncthreads();
  const float inv = 1.0f / (red[0] + red[1] + red[2] + red[3]);

  for (int v = t; v < 1568; v += 256) {
    uint4 u = p4[v];
    u32 w[4] = {u.x, u.y, u.z, u.w};
    #pragma unroll
    for (int q = 0; q < 4; ++q) {
      const float a = __expf(bf2f((u16)(w[q] & 0xFFFFu)) - mx) * inv;
      const float b = __expf(bf2f((u16)(w[q] >> 16)) - mx) * inv;
      w[q] = (u32)f2bf(a) | ((u32)f2bf(b) << 16);
    }
    p4[v] = make_uint4(w[0], w[1], w[2], w[3]);
  }
}

// ---------------------------------------------------------------------------
// Fused transform-reduce + gating. parts: [S][768][4704] fp32 (channel-major)
// ---------------------------------------------------------------------------
__global__ __launch_bounds__(256) void treduce_gate(
    const float* __restrict__ parts, const float* __restrict__ bt,
    const float* __restrict__ h, float* __restrict__ out, int S)
{
  const long i = (long)blockIdx.x * 256 + threadIdx.x;
  if (i >= 6L * 256 * 196) return;
  const int p4 = (int)(i % 196);
  const int rest = (int)(i / 196);
  const int cs = rest % 256, im = rest / 256;
  const long slice4 = (768L * 4704) >> 2;
  const long colBase = ((long)im * 784) >> 2;
  f32x4v F = {0,0,0,0}, U = {0,0,0,0}, NV = {0,0,0,0};
  for (int s = 0; s < S; ++s) {
    const f32x4v* P = (const f32x4v*)parts + (long)s * slice4;
    F  += P[(((long)cs        * 4704) >> 2) + colBase + p4];
    U  += P[(((long)(256 + cs) * 4704) >> 2) + colBase + p4];
    NV += P[(((long)(512 + cs) * 4704) >> 2) + colBase + p4];
  }
  const float bF = bt[cs], bU = bt[256 + cs], bN = bt[512 + cs];
  const f32x4v hv = ((const f32x4v*)h)[((long)(im * 256 + cs) * 784 >> 2) + p4];
  f32x4v o;
  #pragma unroll
  for (int q = 0; q < 4; ++q) {
    const float f = F[q] + bF, u = U[q] + bU, nv = NV[q] + bN;
    const float sf = 1.0f / (1.0f + __expf(-f));
    const float su = 1.0f / (1.0f + __expf(-u));
    const float e2 = __expf(2.0f * nv);
    const float tv = (e2 - 1.0f) / (e2 + 1.0f);
    o[q] = sf * hv[q] * (1.0f - su) + su * tv;
  }
  ((f32x4v*)out)[((long)(im * 256 + cs) * 784 >> 2) + p4] = o;
}

__global__ __launch_bounds__(256) void fill_sentinel(float* p, long n) {
  const long i = (long)blockIdx.x * 256 + threadIdx.x;
  if (i < n) p[i] = 12345.0f;
}

// ---------------------------------------------------------------------------
extern "C" void kernel_launch(void* const* d_in, const int* in_sizes, int n_in,
                              void* d_out, int out_size, void* d_ws, size_t ws_size,
                              hipStream_t stream) {
  const float* f16 = (const float*)d_in[0];
  const float* mk  = (const float*)d_in[1];
  const float* mv  = (const float*)d_in[2];
  const float* hin = (const float*)d_in[3];
  const float* w1  = (const float*)d_in[4];
  const float* b1  = (const float*)d_in[5];
  const float* w2  = (const float*)d_in[6];
  const float* b2  = (const float*)d_in[7];
  const float* wt  = (const float*)d_in[8];
  const float* bt  = (const float*)d_in[9];
  float* out = (float*)d_out;

  const size_t B_f16T   = 2UL*784*1024*2;
  const size_t B_w1b    = 512UL*1024*2;
  const size_t B_w2R    = 64UL*4608*2;
  const size_t B_out1P  = 2UL*900*512*2;
  const size_t B_qkT    = 2UL*784*64*2;
  const size_t B_concat = 6UL*900*768*2;
  const size_t B_wtR    = 768UL*6912*2;
  const size_t B_mkT    = 2UL*12544*64*2;
  const size_t B_logaff = 2UL*784*12544*2;
  const size_t B_mvb    = 38535168UL*2;
  auto al = [](size_t x) { return (x + 255) & ~(size_t)255; };

  const size_t phase1 = al(B_f16T) + al(B_w1b) + al(B_w2R) + al(B_out1P) + al(B_qkT);
  const size_t regionA = phase1 > al(B_concat) ? phase1 : al(B_concat);

  auto poolFor = [&](int S_ro, int S_tr) -> size_t {
    size_t p1 = 8UL*1568*512*4, p2 = 18UL*64*1568*4;
    size_t pr = (size_t)(2*S_ro)*784*1536*4, pt = (size_t)S_tr*768*4704*4;
    size_t m = p1; if (p2 > m) m = p2; if (pr > m) m = pr; if (pt > m) m = pt;
    return m;
  };
  const size_t fixed = regionA + al(B_wtR) + al(B_mkT) + al(B_logaff) + al(B_mvb);

  // cascade: prefer more K-split (TLP) when workspace allows
  int S_ro = 14, S_tr = 6;
  if (fixed + poolFor(S_ro, S_tr) > ws_size) { S_ro = 7; S_tr = 6; }
  if (fixed + poolFor(S_ro, S_tr) > ws_size) { S_ro = 7; S_tr = 3; }
  if (fixed + poolFor(S_ro, S_tr) > ws_size) { S_ro = 4; S_tr = 3; }
  if (fixed + poolFor(S_ro, S_tr) > ws_size) {
    fill_sentinel<<<4704, 256, 0, stream>>>(out, (long)out_size);
    return;
  }

  char* base = (char*)d_ws;
  size_t off = 0;
  auto alloc = [&](size_t bytes) -> char* { char* p = base + off; off += al(bytes); return p; };
  char* rA = alloc(regionA);
  u16* f16T   = (u16*)rA;
  u16* w1b    = (u16*)(rA + al(B_f16T));
  u16* w2R    = (u16*)(rA + al(B_f16T) + al(B_w1b));
  u16* out1P  = (u16*)(rA + al(B_f16T) + al(B_w1b) + al(B_w2R));
  u16* qkT    = (u16*)(rA + al(B_f16T) + al(B_w1b) + al(B_w2R) + al(B_out1P));
  u16* concatP = (u16*)rA;  // overlays phase-1 buffers (dead by then)
  u16*   wtR    = (u16*)alloc(B_wtR);
  u16*   mkT    = (u16*)alloc(B_mkT);
  u16*   logaff = (u16*)alloc(B_logaff);
  u16*   mvb    = (u16*)alloc(B_mvb);
  float* parts  = (float*)alloc(poolFor(S_ro, S_tr));

  // ---- zero padded conv1 image ----
  zfill<<<512, 256, 0, stream>>>((u32*)out1P, (long)(B_out1P / 4));

  // ---- operand prep ----
  convert_bf<<<256, 256, 0, stream>>>(w1, w1b, 65536);
  permute_w<<<1152, 256, 0, stream>>>(w2, w2R, 64, 512);
  permute_w<<<20736, 256, 0, stream>>>(wt, wtR, 768, 768);
  transpose_bf<<<dim3(25, 32, 2), 256, 0, stream>>>(f16, f16T, 1024, 784, 784L*1024, 1024, 0);
  transpose_bf<<<dim3(392, 2, 2), 256, 0, stream>>>(mk, mkT, 64, 12544, 12544L*64, 64, 0);
  convert_bf<<<18816, 256, 0, stream>>>(mv, mvb, 4816896);

  // ---- conv1 (1x1): A=f16T[1568][1024], B=w1b[512][1024], S=8 ----
  gemm256<0><<<dim3(7, 2, 8), 512, 0, stream>>>(
      f16T, w1b, parts, 1568, 512, 128, 1024, 8, 0, 0, 1568L*512, 0);
  reduce_c1_cl<<<784, 256, 0, stream>>>(parts, out1P, b1, 8);

  // ---- conv2 (3x3 implicit 128-tile): M=64, Cin=512, Ntot=1568, S=18 ----
  conv_glds<<<dim3(1, 13, 18), 256, 0, stream>>>(w2R, out1P, parts, 64, 512, 1568, 256);
  reduceT_qk<<<dim3(2, 25, 2), 256, 0, stream>>>(parts, qkT, b2, 18);

  // ---- logits: M=784, N=12544, K=64 -> bf16, scale 1/8 ----
  gemm_glds<64, 1><<<dim3(7, 98, 2), 256, 0, stream>>>(
      qkT, mkT, logaff, 784, 12544, 64, 64, 1,
      784L*64, 12544L*64, 784L*12544, 0.125f);

  // ---- softmax over memory axis ----
  softmax_inplace<<<1568, 256, 0, stream>>>(logaff);

  // ---- zero concat image, fill h channels ----
  zfill<<<2048, 256, 0, stream>>>((u32*)concatP, (long)(B_concat / 4));
  transT_h<<<dim3(8, 25, 6), 256, 0, stream>>>(hin, concatP);

  // ---- readout: A=logaff[784][12544], B=mvb[1536][12544], per batch ----
  gemm256<0><<<dim3(4, 6, 2 * S_ro), 512, 0, stream>>>(
      logaff, mvb, parts, 784, 1536, 12544 / S_ro, 12544, S_ro,
      784L*12544, 1536L*12544, 784L*1536, 0);
  reduce_ro_cl<<<2352, 256, 0, stream>>>(parts, concatP, S_ro);

  // ---- transform conv: A=wtR[768][9*768], B=concatP pixels, S_tr ----
  gemm256<1><<<dim3(3, 19, S_tr), 512, 0, stream>>>(
      wtR, concatP, parts, 768, 4704, 6912 / S_tr, 6912, S_tr,
      0, 0, 768L*4704, 768);

  // ---- fused reduce + gating -> d_out ----
  treduce_gate<<<1176, 256, 0, stream>>>(parts, bt, hin, out, S_tr);
}

// Round 5
// 467.667 us; speedup vs baseline: 1.0254x; 1.0254x over previous
//
#include <hip/hip_runtime.h>

typedef unsigned short u16;
typedef unsigned int u32;
typedef float f32x4v __attribute__((ext_vector_type(4)));
typedef __bf16 bf16x8 __attribute__((ext_vector_type(8)));

#define GAS __attribute__((address_space(1)))
#define LAS __attribute__((address_space(3)))

__device__ __forceinline__ u16 f2bf(float f) {
  u32 u = __builtin_bit_cast(u32, f);
  u32 r = (u + 0x7FFFu + ((u >> 16) & 1u)) >> 16;  // RNE
  return (u16)r;
}
__device__ __forceinline__ float bf2f(u16 h) {
  return __builtin_bit_cast(float, (u32)h << 16);
}
__device__ __forceinline__ void gld_lds16(const void* g, void* l) {
  __builtin_amdgcn_global_load_lds((const GAS void*)g, (LAS void*)l, 16, 0, 0);
}
#define VMCNT(N) asm volatile("s_waitcnt vmcnt(" #N ")" ::: "memory")

// ---------------------------------------------------------------------------
// 256x256 MFMA GEMM, BK=32, 512 thr / 8 waves, per-wave 128x64 output.
// Counted-vmcnt pipeline (T4): stage(next) -> vmcnt(4) -> s_barrier ->
// ds_read+MFMA -> s_barrier. Next-tile loads stay in flight across barriers.
// LDS chunk-XOR swizzle (T2, both-sides): stage source chunk ^= (t>>4)&3,
// reader chunk = hi ^ (lr>>2) — compile-time per-thread, conflict-free-ish.
//   C[m][n] = sum_k A[m][k] * B[n][k]; fp32 partial at Cp + z*strC.
// CONV=1: B is zero-padded channel-last image stack [nImg][900][Cin].
// ---------------------------------------------------------------------------
template <int CONV>
__global__ __launch_bounds__(512) void gemm256(
    const u16* __restrict__ A, const u16* __restrict__ B, float* __restrict__ Cp,
    int M, int N, int Kc, int fullK, int S,
    long strA, long strB, long strC, int Cin)
{
  __shared__ u16 sA[2][256 * 32];
  __shared__ u16 sB[2][256 * 32];
  const int t = threadIdx.x, lane = t & 63, wave = t >> 6;
  const int z = blockIdx.z, zb = z / S, s = z - zb * S;
  const int m0 = blockIdx.x * 256, n0 = blockIdx.y * 256;
  const int kbeg = s * Kc;

  // staging: issue q in {0,1}: row = q*128 + (t>>2); source 16B chunk is
  // XOR-swizzled so linear LDS holds swizzled layout (rule #21 both-sides).
  const int schunk = ((t & 3) ^ ((t >> 4) & 3)) * 8;
  const u16* Ap[2]; const u16* Bp[2];
  #pragma unroll
  for (int q = 0; q < 2; ++q) {
    int ra = m0 + q * 128 + (t >> 2); if (ra >= M) ra = M - 1;
    Ap[q] = A + (long)zb * strA + (long)ra * fullK + schunk;
    if constexpr (CONV) {
      int pn = n0 + q * 128 + (t >> 2); if (pn >= N) pn = 0;
      const int img = pn / 784, p = pn - img * 784;
      const int py = p / 28, px = p - py * 28;
      Bp[q] = B + ((long)img * 900 + (py + 1) * 30 + (px + 1)) * Cin + schunk;
    } else {
      int rb = n0 + q * 128 + (t >> 2); if (rb >= N) rb = N - 1;
      Bp[q] = B + (long)zb * strB + (long)rb * fullK + schunk;
    }
  }
  const int ldst = wave * 512 + lane * 8;  // u16 units

  auto stage = [&](int buf, int kg) {
    long boff;
    if constexpr (CONV) {
      const int tap = kg / Cin, kc = kg - tap * Cin;
      boff = (long)((tap / 3 - 1) * 30 + (tap % 3 - 1)) * Cin + kc;
    } else {
      boff = kg;
    }
    #pragma unroll
    for (int q = 0; q < 2; ++q) {
      gld_lds16(Ap[q] + kg,   &sA[buf][q * 4096 + ldst]);
      gld_lds16(Bp[q] + boff, &sB[buf][q * 4096 + ldst]);
    }
  };

  const int wrow = (wave & 1) * 128, wcol = (wave >> 1) * 64;
  const int lr = lane & 15, hi = lane >> 4;
  const int csw = (hi ^ (lr >> 2)) * 8;   // swizzled read chunk (u16 units)
  f32x4v acc[8][4] = {};
  const int niter = Kc >> 5;

  stage(0, kbeg);
  for (int it = 0; it < niter; ++it) {
    const int cur = it & 1;
    if (it + 1 < niter) {
      stage(cur ^ 1, kbeg + (it + 1) * 32);
      VMCNT(4);               // wait current buf's 4 loads; next 4 keep flying
    } else {
      VMCNT(0);
    }
    __builtin_amdgcn_s_barrier();
    __builtin_amdgcn_sched_barrier(0);
    bf16x8 af[8], bf[4];
    #pragma unroll
    for (int m = 0; m < 8; ++m) af[m] = *(const bf16x8*)&sA[cur][(wrow + m*16 + lr) * 32 + csw];
    #pragma unroll
    for (int n = 0; n < 4; ++n) bf[n] = *(const bf16x8*)&sB[cur][(wcol + n*16 + lr) * 32 + csw];
    __builtin_amdgcn_s_setprio(1);
    #pragma unroll
    for (int m = 0; m < 8; ++m)
      #pragma unroll
      for (int n = 0; n < 4; ++n)
        acc[m][n] = __builtin_amdgcn_mfma_f32_16x16x32_bf16(af[m], bf[n], acc[m][n], 0, 0, 0);
    __builtin_amdgcn_s_setprio(0);
    __builtin_amdgcn_sched_barrier(0);
    __builtin_amdgcn_s_barrier();
  }

  // D: lane l reg r -> row=(l>>4)*4+r, col=l&15
  float* Co = Cp + (long)z * strC;
  const int lq = hi * 4;
  #pragma unroll
  for (int m = 0; m < 8; ++m)
    #pragma unroll
    for (int r = 0; r < 4; ++r) {
      const int row = m0 + wrow + m * 16 + lq + r;
      if (row >= M) continue;
      #pragma unroll
      for (int n = 0; n < 4; ++n) {
        const int col = n0 + wcol + n * 16 + lr;
        if (col < N) Co[(long)row * N + col] = acc[m][n][r];
      }
    }
}

// ---------------------------------------------------------------------------
// 128x128 glds GEMM (logits). Counted-vmcnt schedule. OUT=1: bf16 *scale.
// ---------------------------------------------------------------------------
template <int BK, int OUT>
__global__ __launch_bounds__(256) void gemm_glds(
    const u16* __restrict__ A, const u16* __restrict__ B, void* __restrict__ C,
    int M, int N, int Kc, int fullK, int S,
    long strA, long strB, long strC, float scale)
{
  constexpr int CPR = BK / 8;
  constexpr int ISS = BK / 16;
  __shared__ u16 sA[2][128 * BK];
  __shared__ u16 sB[2][128 * BK];
  const int t = threadIdx.x, lane = t & 63, wave = t >> 6;
  const int z = blockIdx.z, zb = z / S, s = z - zb * S;
  const int m0 = blockIdx.x * 128, n0 = blockIdx.y * 128;
  const int kbeg = s * Kc;

  const u16* Aptr[ISS]; const u16* Bptr[ISS]; int lofs[ISS];
  #pragma unroll
  for (int i = 0; i < ISS; ++i) {
    const int tp = i * 256 + t;
    const int r = tp / CPR;
    int c16 = tp % CPR;
    if constexpr (BK == 32) c16 = c16 ^ ((tp >> 4) & 3);   // swizzle source
    int ra = m0 + r; if (ra >= M) ra = M - 1;
    int rb = n0 + r; if (rb >= N) rb = N - 1;
    Aptr[i] = A + (long)zb * strA + (long)ra * fullK + kbeg + c16 * 8;
    Bptr[i] = B + (long)zb * strB + (long)rb * fullK + kbeg + c16 * 8;
    lofs[i] = (i * 256 + (wave << 6)) * 8;
  }
  auto stage = [&](int buf, int k0) {
    #pragma unroll
    for (int i = 0; i < ISS; ++i) {
      gld_lds16(Aptr[i] + k0, &sA[buf][lofs[i]]);
      gld_lds16(Bptr[i] + k0, &sB[buf][lofs[i]]);
    }
  };

  const int wr = (wave >> 1) * 64, wc = (wave & 1) * 64;
  const int lr = lane & 15, hi = lane >> 4;
  f32x4v acc[4][4] = {};
  const int niter = Kc / BK;

  stage(0, 0);
  for (int it = 0; it < niter; ++it) {
    const int cur = it & 1;
    if (it + 1 < niter) {
      stage(cur ^ 1, (it + 1) * BK);
      if constexpr (ISS == 2) VMCNT(4); else VMCNT(8);
    } else {
      VMCNT(0);
    }
    __builtin_amdgcn_s_barrier();
    __builtin_amdgcn_sched_barrier(0);
    #pragma unroll
    for (int kk = 0; kk < BK; kk += 32) {
      int lk = kk + hi * 8;
      if constexpr (BK == 32) lk = kk + ((hi ^ (lr >> 2)) * 8);
      bf16x8 af[4], bv[4];
      #pragma unroll
      for (int i = 0; i < 4; ++i) af[i] = *(const bf16x8*)&sA[cur][(wr + i*16 + lr) * BK + lk];
      #pragma unroll
      for (int j = 0; j < 4; ++j) bv[j] = *(const bf16x8*)&sB[cur][(wc + j*16 + lr) * BK + lk];
      __builtin_amdgcn_s_setprio(1);
      #pragma unroll
      for (int i = 0; i < 4; ++i)
        #pragma unroll
        for (int j = 0; j < 4; ++j)
          acc[i][j] = __builtin_amdgcn_mfma_f32_16x16x32_bf16(af[i], bv[j], acc[i][j], 0, 0, 0);
      __builtin_amdgcn_s_setprio(0);
    }
    __builtin_amdgcn_sched_barrier(0);
    __builtin_amdgcn_s_barrier();
  }

  const int lq = hi * 4;
  if constexpr (OUT == 0) {
    float* Cp = (float*)C + (long)z * strC;
    #pragma unroll
    for (int i = 0; i < 4; ++i)
      #pragma unroll
      for (int r = 0; r < 4; ++r) {
        const int row = m0 + wr + i*16 + lq + r;
        if (row >= M) continue;
        #pragma unroll
        for (int j = 0; j < 4; ++j) {
          const int col = n0 + wc + j*16 + lr;
          if (col < N) Cp[(long)row * N + col] = acc[i][j][r];
        }
      }
  } else {
    u16* Cp = (u16*)C + (long)zb * strC;
    #pragma unroll
    for (int i = 0; i < 4; ++i)
      #pragma unroll
      for (int r = 0; r < 4; ++r) {
        const int row = m0 + wr + i*16 + lq + r;
        if (row >= M) continue;
        #pragma unroll
        for (int j = 0; j < 4; ++j) {
          const int col = n0 + wc + j*16 + lr;
          if (col < N) Cp[(long)row * N + col] = f2bf(acc[i][j][r] * scale);
        }
      }
  }
}

// ---------------------------------------------------------------------------
// 128x128 implicit-conv (conv2: M=64). Counted-vmcnt + swizzle.
// ---------------------------------------------------------------------------
__global__ __launch_bounds__(256) void conv_glds(
    const u16* __restrict__ Wt, const u16* __restrict__ imgP,
    float* __restrict__ Cp, int M, int Cin, int Ntot, int Kc)
{
  __shared__ u16 sA[2][128 * 32];
  __shared__ u16 sB[2][128 * 32];
  const int t = threadIdx.x, lane = t & 63, wave = t >> 6;
  const int z = blockIdx.z;
  const int m0 = blockIdx.x * 128, n0 = blockIdx.y * 128;
  const int kbeg = z * Kc;

  const u16* Aptr[2]; const u16* Bptr[2]; int lofs[2];
  #pragma unroll
  for (int i = 0; i < 2; ++i) {
    const int tp = i * 256 + t;
    const int r = tp >> 2;
    const int c16 = (tp & 3) ^ ((tp >> 4) & 3);  // swizzled source chunk
    int ra = m0 + r; if (ra >= M) ra = M - 1;
    int pn = n0 + r; if (pn >= Ntot) pn = 0;
    const int img = pn / 784, p = pn - img * 784;
    const int py = p / 28, px = p - py * 28;
    Aptr[i] = Wt + (long)ra * (9 * Cin) + c16 * 8;
    Bptr[i] = imgP + ((long)img * 900 + (py + 1) * 30 + (px + 1)) * Cin + c16 * 8;
    lofs[i] = (i * 256 + (wave << 6)) * 8;
  }
  auto stage = [&](int buf, int kg) {
    const int tap = kg / Cin, kc = kg - tap * Cin;
    const long off = (long)((tap / 3 - 1) * 30 + (tap % 3 - 1)) * Cin + kc;
    #pragma unroll
    for (int i = 0; i < 2; ++i) {
      gld_lds16(Aptr[i] + kg, &sA[buf][lofs[i]]);
      gld_lds16(Bptr[i] + off, &sB[buf][lofs[i]]);
    }
  };

  const int wr = (wave >> 1) * 64, wc = (wave & 1) * 64;
  const int lr = lane & 15, hi = lane >> 4;
  const int csw = (hi ^ (lr >> 2)) * 8;
  f32x4v acc[4][4] = {};
  const int niter = Kc >> 5;

  stage(0, kbeg);
  for (int it = 0; it < niter; ++it) {
    const int cur = it & 1;
    if (it + 1 < niter) {
      stage(cur ^ 1, kbeg + (it + 1) * 32);
      VMCNT(4);
    } else {
      VMCNT(0);
    }
    __builtin_amdgcn_s_barrier();
    __builtin_amdgcn_sched_barrier(0);
    bf16x8 af[4], bv[4];
    #pragma unroll
    for (int i = 0; i < 4; ++i) af[i] = *(const bf16x8*)&sA[cur][(wr + i*16 + lr) * 32 + csw];
    #pragma unroll
    for (int j = 0; j < 4; ++j) bv[j] = *(const bf16x8*)&sB[cur][(wc + j*16 + lr) * 32 + csw];
    __builtin_amdgcn_s_setprio(1);
    #pragma unroll
    for (int i = 0; i < 4; ++i)
      #pragma unroll
      for (int j = 0; j < 4; ++j)
        acc[i][j] = __builtin_amdgcn_mfma_f32_16x16x32_bf16(af[i], bv[j], acc[i][j], 0, 0, 0);
    __builtin_amdgcn_s_setprio(0);
    __builtin_amdgcn_sched_barrier(0);
    __builtin_amdgcn_s_barrier();
  }

  float* Co = Cp + (long)z * M * Ntot;
  const int lq = hi * 4;
  #pragma unroll
  for (int i = 0; i < 4; ++i)
    #pragma unroll
    for (int r = 0; r < 4; ++r) {
      const int row = m0 + wr + i*16 + lq + r;
      if (row >= M) continue;
      #pragma unroll
      for (int j = 0; j < 4; ++j) {
        const int col = n0 + wc + j*16 + lr;
        if (col < Ntot) Co[(long)row * Ntot + col] = acc[i][j][r];
      }
    }
}

// ---------------------------------------------------------------------------
// Helpers: transpose fp32->bf16, convert, weight permute, zero-fill
// ---------------------------------------------------------------------------
__global__ __launch_bounds__(256) void transpose_bf(
    const float* __restrict__ in, u16* __restrict__ out,
    int R, int C, long strOutZ, int ldOut, int colOff)
{
  __shared__ float tile[32][33];
  in  += (long)blockIdx.z * R * C;
  out += (long)blockIdx.z * strOutZ;
  const int c0 = blockIdx.x * 32, r0 = blockIdx.y * 32;
  const int tx = threadIdx.x & 31, ty = threadIdx.x >> 5;
  for (int i = ty; i < 32; i += 8) {
    const int r = r0 + i, c = c0 + tx;
    tile[i][tx] = (r < R && c < C) ? in[(long)r * C + c] : 0.0f;
  }
  __syncthreads();
  for (int i = ty; i < 32; i += 8) {
    const int r = r0 + tx, c = c0 + i;
    if (c < C && r < R)
      out[(long)c * ldOut + colOff + r] = f2bf(tile[tx][i]);
  }
}

__global__ __launch_bounds__(256) void convert_bf(
    const float* __restrict__ in, u16* __restrict__ out, long n8)
{
  const long i = (long)blockIdx.x * 256 + threadIdx.x;
  if (i >= n8) return;
  const float4* p = (const float4*)in + i * 2;
  const float4 a = p[0], b = p[1];
  u16 o[8] = {f2bf(a.x), f2bf(a.y), f2bf(a.z), f2bf(a.w),
              f2bf(b.x), f2bf(b.y), f2bf(b.z), f2bf(b.w)};
  ((uint4*)out)[i] = *(uint4*)o;
}

__global__ __launch_bounds__(256) void permute_w(
    const float* __restrict__ src, u16* __restrict__ dst, int M, int Cin)
{
  const long total = (long)M * 9 * Cin;
  const long idx = (long)blockIdx.x * 256 + threadIdx.x;
  if (idx >= total) return;
  const int c = (int)(idx % Cin);
  const int tap = (int)((idx / Cin) % 9);
  const int m = (int)(idx / ((long)9 * Cin));
  dst[idx] = f2bf(src[((long)m * Cin + c) * 9 + tap]);
}

__global__ __launch_bounds__(256) void zfill(u32* __restrict__ p, long n) {
  const long stride = (long)gridDim.x * 256;
  for (long i = (long)blockIdx.x * 256 + threadIdx.x; i < n; i += stride) p[i] = 0;
}

// ---------------------------------------------------------------------------
// Reduce kernels
// ---------------------------------------------------------------------------
// conv1: parts[S][1568][512] (pixel-major) -> out1P[b][900pad][512] bf16 +b1
__global__ __launch_bounds__(256) void reduce_c1_cl(
    const float* __restrict__ parts, u16* __restrict__ dst,
    const float* __restrict__ bias, int S)
{
  const long idx = (long)blockIdx.x * 256 + threadIdx.x;
  if (idx >= 1568L * 128) return;
  const int c4 = (int)(idx & 127), p = (int)(idx >> 7);
  const int c = c4 * 4;
  f32x4v sum = *(const f32x4v*)&bias[c];
  for (int s = 0; s < S; ++s)
    sum += *(const f32x4v*)&parts[((long)s * 1568 + p) * 512 + c];
  const int im = p / 784, q = p - im * 784;
  const int qpad = (q / 28 + 1) * 30 + (q % 28 + 1);
  u16 o[4] = {f2bf(sum[0]), f2bf(sum[1]), f2bf(sum[2]), f2bf(sum[3])};
  *(uint2*)&dst[((long)im * 900 + qpad) * 512 + c] = *(uint2*)o;
}

// readout: parts[(b*S+s)][784][1536] -> concatP[b*3+n][900pad][768] ch 0..511
__global__ __launch_bounds__(256) void reduce_ro_cl(
    const float* __restrict__ parts, u16* __restrict__ dst, int S)
{
  const long idx = (long)blockIdx.x * 256 + threadIdx.x;
  if (idx >= 2L * 784 * 384) return;
  const int c4 = (int)(idx % 384);
  const long rest = idx / 384;
  const int p = (int)(rest % 784), b = (int)(rest / 784);
  const int c = c4 * 4;
  f32x4v sum = {0, 0, 0, 0};
  for (int s = 0; s < S; ++s)
    sum += *(const f32x4v*)&parts[((long)(b * S + s) * 784 + p) * 1536 + c];
  const int n = c >> 9, cc = c & 511;
  const int qpad = (p / 28 + 1) * 30 + (p % 28 + 1);
  u16 o[4] = {f2bf(sum[0]), f2bf(sum[1]), f2bf(sum[2]), f2bf(sum[3])};
  *(uint2*)&dst[((long)(b * 3 + n) * 900 + qpad) * 768 + cc] = *(uint2*)o;
}

// conv2: parts[S][64][1568] -> qkT[b][784][64] (+b2)
__global__ __launch_bounds__(256) void reduceT_qk(
    const float* __restrict__ parts, u16* __restrict__ dst,
    const float* __restrict__ bias, int S)
{
  __shared__ float tile[32][33];
  const int b = blockIdx.z, c0 = blockIdx.x * 32, p0 = blockIdx.y * 32;
  const int tx = threadIdx.x & 31, ty = threadIdx.x >> 5;
  for (int i = ty; i < 32; i += 8) {
    const int pc = min(p0 + tx, 783);
    const long base = (long)(c0 + i) * 1568 + b * 784 + pc;
    float s = 0;
    for (int k = 0; k < S; ++k) s += parts[(long)k * 64 * 1568 + base];
    tile[i][tx] = s;
  }
  __syncthreads();
  for (int i = ty; i < 32; i += 8) {
    const int p = p0 + i, c = c0 + tx;
    if (p < 784)
      dst[((long)b * 784 + p) * 64 + c] = f2bf(tile[tx][i] + bias[c]);
  }
}

// h: hin[img][256][784] -> concatP[img][900pad][ch 512..767]
__global__ __launch_bounds__(256) void transT_h(
    const float* __restrict__ h, u16* __restrict__ dst)
{
  __shared__ float tile[32][33];
  const int zimg = blockIdx.z, c0 = blockIdx.x * 32, p0 = blockIdx.y * 32;
  const int tx = threadIdx.x & 31, ty = threadIdx.x >> 5;
  for (int i = ty; i < 32; i += 8) {
    const int pc = min(p0 + tx, 783);
    tile[i][tx] = h[((long)zimg * 256 + c0 + i) * 784 + pc];
  }
  __syncthreads();
  for (int i = ty; i < 32; i += 8) {
    const int p = p0 + i, c = c0 + tx;
    if (p < 784) {
      const int qpad = (p / 28 + 1) * 30 + (p % 28 + 1);
      dst[((long)zimg * 900 + qpad) * 768 + 512 + c] = f2bf(tile[tx][i]);
    }
  }
}

// ---------------------------------------------------------------------------
// In-place softmax over rows of 12544 bf16 (one block per row)
// ---------------------------------------------------------------------------
__global__ __launch_bounds__(256) void softmax_inplace(u16* __restrict__ buf)
{
  u16* ptr = buf + (long)blockIdx.x * 12544;
  uint4* p4 = (uint4*)ptr;
  const int t = threadIdx.x;
  __shared__ float red[4];
  float mx = -3.0e38f;
  for (int v = t; v < 1568; v += 256) {
    uint4 u = p4[v];
    const u32 w[4] = {u.x, u.y, u.z, u.w};
    #pragma unroll
    for (int q = 0; q < 4; ++q) {
      mx = fmaxf(mx, bf2f((u16)(w[q] & 0xFFFFu)));
      mx = fmaxf(mx, bf2f((u16)(w[q] >> 16)));
    }
  }
  #pragma unroll
  for (int o = 32; o > 0; o >>= 1) mx = fmaxf(mx, __shfl_xor(mx, o));
  if ((t & 63) == 0) red[t >> 6] = mx;
  __syncthreads();
  mx = fmaxf(fmaxf(red[0], red[1]), fmaxf(red[2], red[3]));

  float s = 0.0f;
  for (int v = t; v < 1568; v += 256) {
    uint4 u = p4[v];
    const u32 w[4] = {u.x, u.y, u.z, u.w};
    #pragma unroll
    for (int q = 0; q < 4; ++q) {
      s += __expf(bf2f((u16)(w[q] & 0xFFFFu)) - mx);
      s += __expf(bf2f((u16)(w[q] >> 16)) - mx);
    }
  }
  #pragma unroll
  for (int o = 32; o > 0; o >>= 1) s += __shfl_xor(s, o);
  __syncthreads();
  if ((t & 63) == 0) red[t >> 6] = s;
  __syncthreads();
  const float inv = 1.0f / (red[0] + red[1] + red[2] + red[3]);

  for (int v = t; v < 1568; v += 256) {
    uint4 u = p4[v];
    u32 w[4] = {u.x, u.y, u.z, u.w};
    #pragma unroll
    for (int q = 0; q < 4; ++q) {
      const float a = __expf(bf2f((u16)(w[q] & 0xFFFFu)) - mx) * inv;
      const float b = __expf(bf2f((u16)(w[q] >> 16)) - mx) * inv;
      w[q] = (u32)f2bf(a) | ((u32)f2bf(b) << 16);
    }
    p4[v] = make_uint4(w[0], w[1], w[2], w[3]);
  }
}

// ---------------------------------------------------------------------------
// Fused transform-reduce + gating. parts: [S][768][4704] fp32 (channel-major)
// ---------------------------------------------------------------------------
__global__ __launch_bounds__(256) void treduce_gate(
    const float* __restrict__ parts, const float* __restrict__ bt,
    const float* __restrict__ h, float* __restrict__ out, int S)
{
  const long i = (long)blockIdx.x * 256 + threadIdx.x;
  if (i >= 6L * 256 * 196) return;
  const int p4 = (int)(i % 196);
  const int rest = (int)(i / 196);
  const int cs = rest % 256, im = rest / 256;
  const long slice4 = (768L * 4704) >> 2;
  const long colBase = ((long)im * 784) >> 2;
  f32x4v F = {0,0,0,0}, U = {0,0,0,0}, NV = {0,0,0,0};
  for (int s = 0; s < S; ++s) {
    const f32x4v* P = (const f32x4v*)parts + (long)s * slice4;
    F  += P[(((long)cs        * 4704) >> 2) + colBase + p4];
    U  += P[(((long)(256 + cs) * 4704) >> 2) + colBase + p4];
    NV += P[(((long)(512 + cs) * 4704) >> 2) + colBase + p4];
  }
  const float bF = bt[cs], bU = bt[256 + cs], bN = bt[512 + cs];
  const f32x4v hv = ((const f32x4v*)h)[((long)(im * 256 + cs) * 784 >> 2) + p4];
  f32x4v o;
  #pragma unroll
  for (int q = 0; q < 4; ++q) {
    const float f = F[q] + bF, u = U[q] + bU, nv = NV[q] + bN;
    const float sf = 1.0f / (1.0f + __expf(-f));
    const float su = 1.0f / (1.0f + __expf(-u));
    const float e2 = __expf(2.0f * nv);
    const float tv = (e2 - 1.0f) / (e2 + 1.0f);
    o[q] = sf * hv[q] * (1.0f - su) + su * tv;
  }
  ((f32x4v*)out)[((long)(im * 256 + cs) * 784 >> 2) + p4] = o;
}

__global__ __launch_bounds__(256) void fill_sentinel(float* p, long n) {
  const long i = (long)blockIdx.x * 256 + threadIdx.x;
  if (i < n) p[i] = 12345.0f;
}

// ---------------------------------------------------------------------------
extern "C" void kernel_launch(void* const* d_in, const int* in_sizes, int n_in,
                              void* d_out, int out_size, void* d_ws, size_t ws_size,
                              hipStream_t stream) {
  const float* f16 = (const float*)d_in[0];
  const float* mk  = (const float*)d_in[1];
  const float* mv  = (const float*)d_in[2];
  const float* hin = (const float*)d_in[3];
  const float* w1  = (const float*)d_in[4];
  const float* b1  = (const float*)d_in[5];
  const float* w2  = (const float*)d_in[6];
  const float* b2  = (const float*)d_in[7];
  const float* wt  = (const float*)d_in[8];
  const float* bt  = (const float*)d_in[9];
  float* out = (float*)d_out;

  const size_t B_f16T   = 2UL*784*1024*2;
  const size_t B_w1b    = 512UL*1024*2;
  const size_t B_w2R    = 64UL*4608*2;
  const size_t B_out1P  = 2UL*900*512*2;
  const size_t B_qkT    = 2UL*784*64*2;
  const size_t B_concat = 6UL*900*768*2;
  const size_t B_wtR    = 768UL*6912*2;
  const size_t B_mkT    = 2UL*12544*64*2;
  const size_t B_logaff = 2UL*784*12544*2;
  const size_t B_mvb    = 38535168UL*2;
  auto al = [](size_t x) { return (x + 255) & ~(size_t)255; };

  const size_t phase1 = al(B_f16T) + al(B_w1b) + al(B_w2R) + al(B_out1P) + al(B_qkT);
  const size_t regionA = phase1 > al(B_concat) ? phase1 : al(B_concat);

  auto poolFor = [&](int S_ro, int S_tr) -> size_t {
    size_t p1 = 8UL*1568*512*4, p2 = 18UL*64*1568*4;
    size_t pr = (size_t)(2*S_ro)*784*1536*4, pt = (size_t)S_tr*768*4704*4;
    size_t m = p1; if (p2 > m) m = p2; if (pr > m) m = pr; if (pt > m) m = pt;
    return m;
  };
  const size_t fixed = regionA + al(B_wtR) + al(B_mkT) + al(B_logaff) + al(B_mvb);

  int S_ro = 8, S_tr = 6;
  if (fixed + poolFor(S_ro, S_tr) > ws_size) { S_ro = 8; S_tr = 3; }
  if (fixed + poolFor(S_ro, S_tr) > ws_size) { S_ro = 4; S_tr = 3; }
  if (fixed + poolFor(S_ro, S_tr) > ws_size) {
    fill_sentinel<<<4704, 256, 0, stream>>>(out, (long)out_size);
    return;
  }

  char* base = (char*)d_ws;
  size_t off = 0;
  auto alloc = [&](size_t bytes) -> char* { char* p = base + off; off += al(bytes); return p; };
  char* rA = alloc(regionA);
  u16* f16T   = (u16*)rA;
  u16* w1b    = (u16*)(rA + al(B_f16T));
  u16* w2R    = (u16*)(rA + al(B_f16T) + al(B_w1b));
  u16* out1P  = (u16*)(rA + al(B_f16T) + al(B_w1b) + al(B_w2R));
  u16* qkT    = (u16*)(rA + al(B_f16T) + al(B_w1b) + al(B_w2R) + al(B_out1P));
  u16* concatP = (u16*)rA;  // overlays phase-1 buffers (dead by then)
  u16*   wtR    = (u16*)alloc(B_wtR);
  u16*   mkT    = (u16*)alloc(B_mkT);
  u16*   logaff = (u16*)alloc(B_logaff);
  u16*   mvb    = (u16*)alloc(B_mvb);
  float* parts  = (float*)alloc(poolFor(S_ro, S_tr));

  // ---- zero padded conv1 image ----
  zfill<<<512, 256, 0, stream>>>((u32*)out1P, (long)(B_out1P / 4));

  // ---- operand prep ----
  convert_bf<<<256, 256, 0, stream>>>(w1, w1b, 65536);
  permute_w<<<1152, 256, 0, stream>>>(w2, w2R, 64, 512);
  permute_w<<<20736, 256, 0, stream>>>(wt, wtR, 768, 768);
  transpose_bf<<<dim3(25, 32, 2), 256, 0, stream>>>(f16, f16T, 1024, 784, 784L*1024, 1024, 0);
  transpose_bf<<<dim3(392, 2, 2), 256, 0, stream>>>(mk, mkT, 64, 12544, 12544L*64, 64, 0);
  convert_bf<<<18816, 256, 0, stream>>>(mv, mvb, 4816896);

  // ---- conv1 (1x1): A=f16T[1568][1024], B=w1b[512][1024], S=8 ----
  gemm256<0><<<dim3(7, 2, 8), 512, 0, stream>>>(
      f16T, w1b, parts, 1568, 512, 128, 1024, 8, 0, 0, 1568L*512, 0);
  reduce_c1_cl<<<784, 256, 0, stream>>>(parts, out1P, b1, 8);

  // ---- conv2 (3x3 implicit 128-tile): M=64, Cin=512, Ntot=1568, S=18 ----
  conv_glds<<<dim3(1, 13, 18), 256, 0, stream>>>(w2R, out1P, parts, 64, 512, 1568, 256);
  reduceT_qk<<<dim3(2, 25, 2), 256, 0, stream>>>(parts, qkT, b2, 18);

  // ---- logits: M=784, N=12544, K=64 -> bf16, scale 1/8 ----
  gemm_glds<64, 1><<<dim3(7, 98, 2), 256, 0, stream>>>(
      qkT, mkT, logaff, 784, 12544, 64, 64, 1,
      784L*64, 12544L*64, 784L*12544, 0.125f);

  // ---- softmax over memory axis ----
  softmax_inplace<<<1568, 256, 0, stream>>>(logaff);

  // ---- zero concat image, fill h channels ----
  zfill<<<2048, 256, 0, stream>>>((u32*)concatP, (long)(B_concat / 4));
  transT_h<<<dim3(8, 25, 6), 256, 0, stream>>>(hin, concatP);

  // ---- readout: A=logaff[784][12544], B=mvb[1536][12544], per batch ----
  gemm256<0><<<dim3(4, 6, 2 * S_ro), 512, 0, stream>>>(
      logaff, mvb, parts, 784, 1536, 12544 / S_ro, 12544, S_ro,
      784L*12544, 1536L*12544, 784L*1536, 0);
  reduce_ro_cl<<<2352, 256, 0, stream>>>(parts, concatP, S_ro);

  // ---- transform conv: A=wtR[768][9*768], B=concatP pixels, S_tr ----
  gemm256<1><<<dim3(3, 19, S_tr), 512, 0, stream>>>(
      wtR, concatP, parts, 768, 4704, 6912 / S_tr, 6912, S_tr,
      0, 0, 768L*4704, 768);

  // ---- fused reduce + gating -> d_out ----
  treduce_gate<<<1176, 256, 0, stream>>>(parts, bt, hin, out, S_tr);
}

// Round 6
// 419.903 us; speedup vs baseline: 1.1420x; 1.1138x over previous
//
#include <hip/hip_runtime.h>

typedef unsigned short u16;
typedef unsigned int u32;
typedef float f32x4v __attribute__((ext_vector_type(4)));
typedef __bf16 bf16x8 __attribute__((ext_vector_type(8)));

#define GAS __attribute__((address_space(1)))
#define LAS __attribute__((address_space(3)))

__device__ __forceinline__ u16 f2bf(float f) {
  u32 u = __builtin_bit_cast(u32, f);
  u32 r = (u + 0x7FFFu + ((u >> 16) & 1u)) >> 16;  // RNE
  return (u16)r;
}
__device__ __forceinline__ float bf2f(u16 h) {
  return __builtin_bit_cast(float, (u32)h << 16);
}
__device__ __forceinline__ void gld_lds16(const void* g, void* l) {
  __builtin_amdgcn_global_load_lds((const GAS void*)g, (LAS void*)l, 16, 0, 0);
}
#define VMCNT(N) asm volatile("s_waitcnt vmcnt(" #N ")" ::: "memory")

// ---------------------------------------------------------------------------
// 256x256 MFMA GEMM, BK=32, 512 thr / 8 waves, per-wave 128x64 output.
// DEPTH-4 circular LDS pipeline (128 KB dynamic LDS): 3 K-tiles of prefetch
// cover (~1200 cy) vs ~900 cy HBM latency. Per iter:
//   stage(t+3) -> vmcnt(12) -> s_barrier -> ds_read+MFMA(t) -> s_barrier
// Tail drains vmcnt 8 -> 4 -> 0.
//   C[m][n] = sum_k A[m][k] * B[n][k]; fp32 partial at Cp + z*strC.
// CONV=1: B is zero-padded channel-last image stack [nImg][900][Cin].
// ---------------------------------------------------------------------------
template <int CONV>
__global__ __launch_bounds__(512) void gemm256(
    const u16* __restrict__ A, const u16* __restrict__ B, float* __restrict__ Cp,
    int M, int N, int Kc, int fullK, int S,
    long strA, long strB, long strC, int Cin)
{
  extern __shared__ u16 smem[];                 // 4 bufs x (sA 8192 + sB 8192)
  u16* sA = smem;                               // [4][256*32]
  u16* sB = smem + 4 * 8192;                    // [4][256*32]
  const int t = threadIdx.x, lane = t & 63, wave = t >> 6;
  const int z = blockIdx.z, zb = z / S, s = z - zb * S;
  const int m0 = blockIdx.x * 256, n0 = blockIdx.y * 256;
  const int kbeg = s * Kc;

  // staging: issue q in {0,1}: row = q*128 + (t>>2); 16B chunk = (t&3)^((t>>4)&3)
  const int schunk = ((t & 3) ^ ((t >> 4) & 3)) * 8;
  const u16* Ap[2]; const u16* Bp[2];
  #pragma unroll
  for (int q = 0; q < 2; ++q) {
    int ra = m0 + q * 128 + (t >> 2); if (ra >= M) ra = M - 1;
    Ap[q] = A + (long)zb * strA + (long)ra * fullK + schunk;
    if constexpr (CONV) {
      int pn = n0 + q * 128 + (t >> 2); if (pn >= N) pn = 0;
      const int img = pn / 784, p = pn - img * 784;
      const int py = p / 28, px = p - py * 28;
      Bp[q] = B + ((long)img * 900 + (py + 1) * 30 + (px + 1)) * Cin + schunk;
    } else {
      int rb = n0 + q * 128 + (t >> 2); if (rb >= N) rb = N - 1;
      Bp[q] = B + (long)zb * strB + (long)rb * fullK + schunk;
    }
  }
  const int ldst = wave * 512 + lane * 8;  // u16 units within a buffer

  auto stage = [&](int buf, int kg) {
    long boff;
    if constexpr (CONV) {
      const int tap = kg / Cin, kc = kg - tap * Cin;
      boff = (long)((tap / 3 - 1) * 30 + (tap % 3 - 1)) * Cin + kc;
    } else {
      boff = kg;
    }
    u16* dA = sA + buf * 8192;
    u16* dB = sB + buf * 8192;
    #pragma unroll
    for (int q = 0; q < 2; ++q) {
      gld_lds16(Ap[q] + kg,   &dA[q * 4096 + ldst]);
      gld_lds16(Bp[q] + boff, &dB[q * 4096 + ldst]);
    }
  };

  const int wrow = (wave & 1) * 128, wcol = (wave >> 1) * 64;
  const int lr = lane & 15, hi = lane >> 4;
  const int csw = (hi ^ (lr >> 2)) * 8;   // read chunk (matches staged layout)
  f32x4v acc[8][4] = {};
  const int niter = Kc >> 5;

  // prologue: stage tiles 0,1,2
  for (int p = 0; p < 3 && p < niter; ++p) stage(p & 3, kbeg + p * 32);

  for (int it = 0; it < niter; ++it) {
    const int cur = it & 3;
    if (it + 3 < niter) {
      stage((it + 3) & 3, kbeg + (it + 3) * 32);
      VMCNT(12);                 // tile `it` (issued 3 iters ago) complete
    } else {
      const int rem = niter - 1 - it;
      if (rem >= 3)      VMCNT(12);
      else if (rem == 2) VMCNT(8);
      else if (rem == 1) VMCNT(4);
      else               VMCNT(0);
    }
    __builtin_amdgcn_s_barrier();
    __builtin_amdgcn_sched_barrier(0);
    const u16* cA = sA + cur * 8192;
    const u16* cB = sB + cur * 8192;
    bf16x8 af[8], bf[4];
    #pragma unroll
    for (int m = 0; m < 8; ++m) af[m] = *(const bf16x8*)&cA[(wrow + m*16 + lr) * 32 + csw];
    #pragma unroll
    for (int n = 0; n < 4; ++n) bf[n] = *(const bf16x8*)&cB[(wcol + n*16 + lr) * 32 + csw];
    __builtin_amdgcn_s_setprio(1);
    #pragma unroll
    for (int m = 0; m < 8; ++m)
      #pragma unroll
      for (int n = 0; n < 4; ++n)
        acc[m][n] = __builtin_amdgcn_mfma_f32_16x16x32_bf16(af[m], bf[n], acc[m][n], 0, 0, 0);
    __builtin_amdgcn_s_setprio(0);
    __builtin_amdgcn_sched_barrier(0);
    __builtin_amdgcn_s_barrier();   // W-A-R: next iter stages into buf read here-1
  }

  // D: lane l reg r -> row=(l>>4)*4+r, col=l&15
  float* Co = Cp + (long)z * strC;
  const int lq = hi * 4;
  #pragma unroll
  for (int m = 0; m < 8; ++m)
    #pragma unroll
    for (int r = 0; r < 4; ++r) {
      const int row = m0 + wrow + m * 16 + lq + r;
      if (row >= M) continue;
      #pragma unroll
      for (int n = 0; n < 4; ++n) {
        const int col = n0 + wcol + n * 16 + lr;
        if (col < N) Co[(long)row * N + col] = acc[m][n][r];
      }
    }
}

// ---------------------------------------------------------------------------
// 128x128 glds GEMM (logits). Counted-vmcnt, depth-1. OUT=1: bf16 *scale.
// ---------------------------------------------------------------------------
template <int BK, int OUT>
__global__ __launch_bounds__(256) void gemm_glds(
    const u16* __restrict__ A, const u16* __restrict__ B, void* __restrict__ C,
    int M, int N, int Kc, int fullK, int S,
    long strA, long strB, long strC, float scale)
{
  constexpr int CPR = BK / 8;
  constexpr int ISS = BK / 16;
  __shared__ u16 sA[2][128 * BK];
  __shared__ u16 sB[2][128 * BK];
  const int t = threadIdx.x, lane = t & 63, wave = t >> 6;
  const int z = blockIdx.z, zb = z / S, s = z - zb * S;
  const int m0 = blockIdx.x * 128, n0 = blockIdx.y * 128;
  const int kbeg = s * Kc;

  const u16* Aptr[ISS]; const u16* Bptr[ISS]; int lofs[ISS];
  #pragma unroll
  for (int i = 0; i < ISS; ++i) {
    const int tp = i * 256 + t;
    const int r = tp / CPR;
    int c16 = tp % CPR;
    if constexpr (BK == 32) c16 = c16 ^ ((tp >> 4) & 3);
    int ra = m0 + r; if (ra >= M) ra = M - 1;
    int rb = n0 + r; if (rb >= N) rb = N - 1;
    Aptr[i] = A + (long)zb * strA + (long)ra * fullK + kbeg + c16 * 8;
    Bptr[i] = B + (long)zb * strB + (long)rb * fullK + kbeg + c16 * 8;
    lofs[i] = (i * 256 + (wave << 6)) * 8;
  }
  auto stage = [&](int buf, int k0) {
    #pragma unroll
    for (int i = 0; i < ISS; ++i) {
      gld_lds16(Aptr[i] + k0, &sA[buf][lofs[i]]);
      gld_lds16(Bptr[i] + k0, &sB[buf][lofs[i]]);
    }
  };

  const int wr = (wave >> 1) * 64, wc = (wave & 1) * 64;
  const int lr = lane & 15, hi = lane >> 4;
  f32x4v acc[4][4] = {};
  const int niter = Kc / BK;

  stage(0, 0);
  for (int it = 0; it < niter; ++it) {
    const int cur = it & 1;
    if (it + 1 < niter) {
      stage(cur ^ 1, (it + 1) * BK);
      if constexpr (ISS == 2) VMCNT(4); else VMCNT(8);
    } else {
      VMCNT(0);
    }
    __builtin_amdgcn_s_barrier();
    __builtin_amdgcn_sched_barrier(0);
    #pragma unroll
    for (int kk = 0; kk < BK; kk += 32) {
      int lk = kk + hi * 8;
      if constexpr (BK == 32) lk = kk + ((hi ^ (lr >> 2)) * 8);
      bf16x8 af[4], bv[4];
      #pragma unroll
      for (int i = 0; i < 4; ++i) af[i] = *(const bf16x8*)&sA[cur][(wr + i*16 + lr) * BK + lk];
      #pragma unroll
      for (int j = 0; j < 4; ++j) bv[j] = *(const bf16x8*)&sB[cur][(wc + j*16 + lr) * BK + lk];
      __builtin_amdgcn_s_setprio(1);
      #pragma unroll
      for (int i = 0; i < 4; ++i)
        #pragma unroll
        for (int j = 0; j < 4; ++j)
          acc[i][j] = __builtin_amdgcn_mfma_f32_16x16x32_bf16(af[i], bv[j], acc[i][j], 0, 0, 0);
      __builtin_amdgcn_s_setprio(0);
    }
    __builtin_amdgcn_sched_barrier(0);
    __builtin_amdgcn_s_barrier();
  }

  const int lq = hi * 4;
  if constexpr (OUT == 0) {
    float* Cp = (float*)C + (long)z * strC;
    #pragma unroll
    for (int i = 0; i < 4; ++i)
      #pragma unroll
      for (int r = 0; r < 4; ++r) {
        const int row = m0 + wr + i*16 + lq + r;
        if (row >= M) continue;
        #pragma unroll
        for (int j = 0; j < 4; ++j) {
          const int col = n0 + wc + j*16 + lr;
          if (col < N) Cp[(long)row * N + col] = acc[i][j][r];
        }
      }
  } else {
    u16* Cp = (u16*)C + (long)zb * strC;
    #pragma unroll
    for (int i = 0; i < 4; ++i)
      #pragma unroll
      for (int r = 0; r < 4; ++r) {
        const int row = m0 + wr + i*16 + lq + r;
        if (row >= M) continue;
        #pragma unroll
        for (int j = 0; j < 4; ++j) {
          const int col = n0 + wc + j*16 + lr;
          if (col < N) Cp[(long)row * N + col] = f2bf(acc[i][j][r] * scale);
        }
      }
  }
}

// ---------------------------------------------------------------------------
// 128x128 implicit-conv (conv2: M=64). Counted-vmcnt depth-1.
// ---------------------------------------------------------------------------
__global__ __launch_bounds__(256) void conv_glds(
    const u16* __restrict__ Wt, const u16* __restrict__ imgP,
    float* __restrict__ Cp, int M, int Cin, int Ntot, int Kc)
{
  __shared__ u16 sA[2][128 * 32];
  __shared__ u16 sB[2][128 * 32];
  const int t = threadIdx.x, lane = t & 63, wave = t >> 6;
  const int z = blockIdx.z;
  const int m0 = blockIdx.x * 128, n0 = blockIdx.y * 128;
  const int kbeg = z * Kc;

  const u16* Aptr[2]; const u16* Bptr[2]; int lofs[2];
  #pragma unroll
  for (int i = 0; i < 2; ++i) {
    const int tp = i * 256 + t;
    const int r = tp >> 2;
    const int c16 = (tp & 3) ^ ((tp >> 4) & 3);
    int ra = m0 + r; if (ra >= M) ra = M - 1;
    int pn = n0 + r; if (pn >= Ntot) pn = 0;
    const int img = pn / 784, p = pn - img * 784;
    const int py = p / 28, px = p - py * 28;
    Aptr[i] = Wt + (long)ra * (9 * Cin) + c16 * 8;
    Bptr[i] = imgP + ((long)img * 900 + (py + 1) * 30 + (px + 1)) * Cin + c16 * 8;
    lofs[i] = (i * 256 + (wave << 6)) * 8;
  }
  auto stage = [&](int buf, int kg) {
    const int tap = kg / Cin, kc = kg - tap * Cin;
    const long off = (long)((tap / 3 - 1) * 30 + (tap % 3 - 1)) * Cin + kc;
    #pragma unroll
    for (int i = 0; i < 2; ++i) {
      gld_lds16(Aptr[i] + kg, &sA[buf][lofs[i]]);
      gld_lds16(Bptr[i] + off, &sB[buf][lofs[i]]);
    }
  };

  const int wr = (wave >> 1) * 64, wc = (wave & 1) * 64;
  const int lr = lane & 15, hi = lane >> 4;
  const int csw = (hi ^ (lr >> 2)) * 8;
  f32x4v acc[4][4] = {};
  const int niter = Kc >> 5;

  stage(0, kbeg);
  for (int it = 0; it < niter; ++it) {
    const int cur = it & 1;
    if (it + 1 < niter) {
      stage(cur ^ 1, kbeg + (it + 1) * 32);
      VMCNT(4);
    } else {
      VMCNT(0);
    }
    __builtin_amdgcn_s_barrier();
    __builtin_amdgcn_sched_barrier(0);
    bf16x8 af[4], bv[4];
    #pragma unroll
    for (int i = 0; i < 4; ++i) af[i] = *(const bf16x8*)&sA[cur][(wr + i*16 + lr) * 32 + csw];
    #pragma unroll
    for (int j = 0; j < 4; ++j) bv[j] = *(const bf16x8*)&sB[cur][(wc + j*16 + lr) * 32 + csw];
    __builtin_amdgcn_s_setprio(1);
    #pragma unroll
    for (int i = 0; i < 4; ++i)
      #pragma unroll
      for (int j = 0; j < 4; ++j)
        acc[i][j] = __builtin_amdgcn_mfma_f32_16x16x32_bf16(af[i], bv[j], acc[i][j], 0, 0, 0);
    __builtin_amdgcn_s_setprio(0);
    __builtin_amdgcn_sched_barrier(0);
    __builtin_amdgcn_s_barrier();
  }

  float* Co = Cp + (long)z * M * Ntot;
  const int lq = hi * 4;
  #pragma unroll
  for (int i = 0; i < 4; ++i)
    #pragma unroll
    for (int r = 0; r < 4; ++r) {
      const int row = m0 + wr + i*16 + lq + r;
      if (row >= M) continue;
      #pragma unroll
      for (int j = 0; j < 4; ++j) {
        const int col = n0 + wc + j*16 + lr;
        if (col < Ntot) Co[(long)row * Ntot + col] = acc[i][j][r];
      }
    }
}

// ---------------------------------------------------------------------------
// Helpers
// ---------------------------------------------------------------------------
__global__ __launch_bounds__(256) void transpose_bf(
    const float* __restrict__ in, u16* __restrict__ out,
    int R, int C, long strOutZ, int ldOut, int colOff)
{
  __shared__ float tile[32][33];
  in  += (long)blockIdx.z * R * C;
  out += (long)blockIdx.z * strOutZ;
  const int c0 = blockIdx.x * 32, r0 = blockIdx.y * 32;
  const int tx = threadIdx.x & 31, ty = threadIdx.x >> 5;
  for (int i = ty; i < 32; i += 8) {
    const int r = r0 + i, c = c0 + tx;
    tile[i][tx] = (r < R && c < C) ? in[(long)r * C + c] : 0.0f;
  }
  __syncthreads();
  for (int i = ty; i < 32; i += 8) {
    const int r = r0 + tx, c = c0 + i;
    if (c < C && r < R)
      out[(long)c * ldOut + colOff + r] = f2bf(tile[tx][i]);
  }
}

__global__ __launch_bounds__(256) void convert_bf(
    const float* __restrict__ in, u16* __restrict__ out, long n8)
{
  const long i = (long)blockIdx.x * 256 + threadIdx.x;
  if (i >= n8) return;
  const float4* p = (const float4*)in + i * 2;
  const float4 a = p[0], b = p[1];
  u16 o[8] = {f2bf(a.x), f2bf(a.y), f2bf(a.z), f2bf(a.w),
              f2bf(b.x), f2bf(b.y), f2bf(b.z), f2bf(b.w)};
  ((uint4*)out)[i] = *(uint4*)o;
}

__global__ __launch_bounds__(256) void permute_w(
    const float* __restrict__ src, u16* __restrict__ dst, int M, int Cin)
{
  const long total = (long)M * 9 * Cin;
  const long idx = (long)blockIdx.x * 256 + threadIdx.x;
  if (idx >= total) return;
  const int c = (int)(idx % Cin);
  const int tap = (int)((idx / Cin) % 9);
  const int m = (int)(idx / ((long)9 * Cin));
  dst[idx] = f2bf(src[((long)m * Cin + c) * 9 + tap]);
}

__global__ __launch_bounds__(256) void zfill(u32* __restrict__ p, long n) {
  const long stride = (long)gridDim.x * 256;
  for (long i = (long)blockIdx.x * 256 + threadIdx.x; i < n; i += stride) p[i] = 0;
}

// ---------------------------------------------------------------------------
// Reduce kernels
// ---------------------------------------------------------------------------
__global__ __launch_bounds__(256) void reduce_c1_cl(
    const float* __restrict__ parts, u16* __restrict__ dst,
    const float* __restrict__ bias, int S)
{
  const long idx = (long)blockIdx.x * 256 + threadIdx.x;
  if (idx >= 1568L * 128) return;
  const int c4 = (int)(idx & 127), p = (int)(idx >> 7);
  const int c = c4 * 4;
  f32x4v sum = *(const f32x4v*)&bias[c];
  for (int s = 0; s < S; ++s)
    sum += *(const f32x4v*)&parts[((long)s * 1568 + p) * 512 + c];
  const int im = p / 784, q = p - im * 784;
  const int qpad = (q / 28 + 1) * 30 + (q % 28 + 1);
  u16 o[4] = {f2bf(sum[0]), f2bf(sum[1]), f2bf(sum[2]), f2bf(sum[3])};
  *(uint2*)&dst[((long)im * 900 + qpad) * 512 + c] = *(uint2*)o;
}

__global__ __launch_bounds__(256) void reduce_ro_cl(
    const float* __restrict__ parts, u16* __restrict__ dst, int S)
{
  const long idx = (long)blockIdx.x * 256 + threadIdx.x;
  if (idx >= 2L * 784 * 384) return;
  const int c4 = (int)(idx % 384);
  const long rest = idx / 384;
  const int p = (int)(rest % 784), b = (int)(rest / 784);
  const int c = c4 * 4;
  f32x4v sum = {0, 0, 0, 0};
  for (int s = 0; s < S; ++s)
    sum += *(const f32x4v*)&parts[((long)(b * S + s) * 784 + p) * 1536 + c];
  const int n = c >> 9, cc = c & 511;
  const int qpad = (p / 28 + 1) * 30 + (p % 28 + 1);
  u16 o[4] = {f2bf(sum[0]), f2bf(sum[1]), f2bf(sum[2]), f2bf(sum[3])};
  *(uint2*)&dst[((long)(b * 3 + n) * 900 + qpad) * 768 + cc] = *(uint2*)o;
}

__global__ __launch_bounds__(256) void reduceT_qk(
    const float* __restrict__ parts, u16* __restrict__ dst,
    const float* __restrict__ bias, int S)
{
  __shared__ float tile[32][33];
  const int b = blockIdx.z, c0 = blockIdx.x * 32, p0 = blockIdx.y * 32;
  const int tx = threadIdx.x & 31, ty = threadIdx.x >> 5;
  for (int i = ty; i < 32; i += 8) {
    const int pc = min(p0 + tx, 783);
    const long base = (long)(c0 + i) * 1568 + b * 784 + pc;
    float s = 0;
    for (int k = 0; k < S; ++k) s += parts[(long)k * 64 * 1568 + base];
    tile[i][tx] = s;
  }
  __syncthreads();
  for (int i = ty; i < 32; i += 8) {
    const int p = p0 + i, c = c0 + tx;
    if (p < 784)
      dst[((long)b * 784 + p) * 64 + c] = f2bf(tile[tx][i] + bias[c]);
  }
}

__global__ __launch_bounds__(256) void transT_h(
    const float* __restrict__ h, u16* __restrict__ dst)
{
  __shared__ float tile[32][33];
  const int zimg = blockIdx.z, c0 = blockIdx.x * 32, p0 = blockIdx.y * 32;
  const int tx = threadIdx.x & 31, ty = threadIdx.x >> 5;
  for (int i = ty; i < 32; i += 8) {
    const int pc = min(p0 + tx, 783);
    tile[i][tx] = h[((long)zimg * 256 + c0 + i) * 784 + pc];
  }
  __syncthreads();
  for (int i = ty; i < 32; i += 8) {
    const int p = p0 + i, c = c0 + tx;
    if (p < 784) {
      const int qpad = (p / 28 + 1) * 30 + (p % 28 + 1);
      dst[((long)zimg * 900 + qpad) * 768 + 512 + c] = f2bf(tile[tx][i]);
    }
  }
}

// ---------------------------------------------------------------------------
// In-place softmax over rows of 12544 bf16 (one block per row)
// ---------------------------------------------------------------------------
__global__ __launch_bounds__(256) void softmax_inplace(u16* __restrict__ buf)
{
  u16* ptr = buf + (long)blockIdx.x * 12544;
  uint4* p4 = (uint4*)ptr;
  const int t = threadIdx.x;
  __shared__ float red[4];
  float mx = -3.0e38f;
  for (int v = t; v < 1568; v += 256) {
    uint4 u = p4[v];
    const u32 w[4] = {u.x, u.y, u.z, u.w};
    #pragma unroll
    for (int q = 0; q < 4; ++q) {
      mx = fmaxf(mx, bf2f((u16)(w[q] & 0xFFFFu)));
      mx = fmaxf(mx, bf2f((u16)(w[q] >> 16)));
    }
  }
  #pragma unroll
  for (int o = 32; o > 0; o >>= 1) mx = fmaxf(mx, __shfl_xor(mx, o));
  if ((t & 63) == 0) red[t >> 6] = mx;
  __syncthreads();
  mx = fmaxf(fmaxf(red[0], red[1]), fmaxf(red[2], red[3]));

  float s = 0.0f;
  for (int v = t; v < 1568; v += 256) {
    uint4 u = p4[v];
    const u32 w[4] = {u.x, u.y, u.z, u.w};
    #pragma unroll
    for (int q = 0; q < 4; ++q) {
      s += __expf(bf2f((u16)(w[q] & 0xFFFFu)) - mx);
      s += __expf(bf2f((u16)(w[q] >> 16)) - mx);
    }
  }
  #pragma unroll
  for (int o = 32; o > 0; o >>= 1) s += __shfl_xor(s, o);
  __syncthreads();
  if ((t & 63) == 0) red[t >> 6] = s;
  __syncthreads();
  const float inv = 1.0f / (red[0] + red[1] + red[2] + red[3]);

  for (int v = t; v < 1568; v += 256) {
    uint4 u = p4[v];
    u32 w[4] = {u.x, u.y, u.z, u.w};
    #pragma unroll
    for (int q = 0; q < 4; ++q) {
      const float a = __expf(bf2f((u16)(w[q] & 0xFFFFu)) - mx) * inv;
      const float b = __expf(bf2f((u16)(w[q] >> 16)) - mx) * inv;
      w[q] = (u32)f2bf(a) | ((u32)f2bf(b) << 16);
    }
    p4[v] = make_uint4(w[0], w[1], w[2], w[3]);
  }
}

// ---------------------------------------------------------------------------
// Fused transform-reduce + gating. parts: [S][768][4704] fp32 (channel-major)
// ---------------------------------------------------------------------------
__global__ __launch_bounds__(256) void treduce_gate(
    const float* __restrict__ parts, const float* __restrict__ bt,
    const float* __restrict__ h, float* __restrict__ out, int S)
{
  const long i = (long)blockIdx.x * 256 + threadIdx.x;
  if (i >= 6L * 256 * 196) return;
  const int p4 = (int)(i % 196);
  const int rest = (int)(i / 196);
  const int cs = rest % 256, im = rest / 256;
  const long slice4 = (768L * 4704) >> 2;
  const long colBase = ((long)im * 784) >> 2;
  f32x4v F = {0,0,0,0}, U = {0,0,0,0}, NV = {0,0,0,0};
  for (int s = 0; s < S; ++s) {
    const f32x4v* P = (const f32x4v*)parts + (long)s * slice4;
    F  += P[(((long)cs        * 4704) >> 2) + colBase + p4];
    U  += P[(((long)(256 + cs) * 4704) >> 2) + colBase + p4];
    NV += P[(((long)(512 + cs) * 4704) >> 2) + colBase + p4];
  }
  const float bF = bt[cs], bU = bt[256 + cs], bN = bt[512 + cs];
  const f32x4v hv = ((const f32x4v*)h)[((long)(im * 256 + cs) * 784 >> 2) + p4];
  f32x4v o;
  #pragma unroll
  for (int q = 0; q < 4; ++q) {
    const float f = F[q] + bF, u = U[q] + bU, nv = NV[q] + bN;
    const float sf = 1.0f / (1.0f + __expf(-f));
    const float su = 1.0f / (1.0f + __expf(-u));
    const float e2 = __expf(2.0f * nv);
    const float tv = (e2 - 1.0f) / (e2 + 1.0f);
    o[q] = sf * hv[q] * (1.0f - su) + su * tv;
  }
  ((f32x4v*)out)[((long)(im * 256 + cs) * 784 >> 2) + p4] = o;
}

__global__ __launch_bounds__(256) void fill_sentinel(float* p, long n) {
  const long i = (long)blockIdx.x * 256 + threadIdx.x;
  if (i < n) p[i] = 12345.0f;
}

// ---------------------------------------------------------------------------
extern "C" void kernel_launch(void* const* d_in, const int* in_sizes, int n_in,
                              void* d_out, int out_size, void* d_ws, size_t ws_size,
                              hipStream_t stream) {
  const float* f16 = (const float*)d_in[0];
  const float* mk  = (const float*)d_in[1];
  const float* mv  = (const float*)d_in[2];
  const float* hin = (const float*)d_in[3];
  const float* w1  = (const float*)d_in[4];
  const float* b1  = (const float*)d_in[5];
  const float* w2  = (const float*)d_in[6];
  const float* b2  = (const float*)d_in[7];
  const float* wt  = (const float*)d_in[8];
  const float* bt  = (const float*)d_in[9];
  float* out = (float*)d_out;

  // allow 128 KB dynamic LDS for the deep-pipeline GEMMs (host-side, capture-safe)
  (void)hipFuncSetAttribute((const void*)gemm256<0>,
                            hipFuncAttributeMaxDynamicSharedMemorySize, 131072);
  (void)hipFuncSetAttribute((const void*)gemm256<1>,
                            hipFuncAttributeMaxDynamicSharedMemorySize, 131072);
  constexpr unsigned DSM = 131072;

  const size_t B_f16T   = 2UL*784*1024*2;
  const size_t B_w1b    = 512UL*1024*2;
  const size_t B_w2R    = 64UL*4608*2;
  const size_t B_out1P  = 2UL*900*512*2;
  const size_t B_qkT    = 2UL*784*64*2;
  const size_t B_concat = 6UL*900*768*2;
  const size_t B_wtR    = 768UL*6912*2;
  const size_t B_mkT    = 2UL*12544*64*2;
  const size_t B_logaff = 2UL*784*12544*2;
  const size_t B_mvb    = 38535168UL*2;
  auto al = [](size_t x) { return (x + 255) & ~(size_t)255; };

  const size_t phase1 = al(B_f16T) + al(B_w1b) + al(B_w2R) + al(B_out1P) + al(B_qkT);
  const size_t regionA = phase1 > al(B_concat) ? phase1 : al(B_concat);

  auto poolFor = [&](int S_ro, int S_tr) -> size_t {
    size_t p1 = 8UL*1568*512*4, p2 = 18UL*64*1568*4;
    size_t pr = (size_t)(2*S_ro)*784*1536*4, pt = (size_t)S_tr*768*4704*4;
    size_t m = p1; if (p2 > m) m = p2; if (pr > m) m = pr; if (pt > m) m = pt;
    return m;
  };
  const size_t fixed = regionA + al(B_wtR) + al(B_mkT) + al(B_logaff) + al(B_mvb);

  int S_ro = 8, S_tr = 8;   // Kc: readout 1568 (49 it), transform 864 (27 it)
  if (fixed + poolFor(S_ro, S_tr) > ws_size) { S_ro = 8; S_tr = 6; }
  if (fixed + poolFor(S_ro, S_tr) > ws_size) { S_ro = 8; S_tr = 3; }
  if (fixed + poolFor(S_ro, S_tr) > ws_size) { S_ro = 4; S_tr = 3; }
  if (fixed + poolFor(S_ro, S_tr) > ws_size) {
    fill_sentinel<<<4704, 256, 0, stream>>>(out, (long)out_size);
    return;
  }

  char* base = (char*)d_ws;
  size_t off = 0;
  auto alloc = [&](size_t bytes) -> char* { char* p = base + off; off += al(bytes); return p; };
  char* rA = alloc(regionA);
  u16* f16T   = (u16*)rA;
  u16* w1b    = (u16*)(rA + al(B_f16T));
  u16* w2R    = (u16*)(rA + al(B_f16T) + al(B_w1b));
  u16* out1P  = (u16*)(rA + al(B_f16T) + al(B_w1b) + al(B_w2R));
  u16* qkT    = (u16*)(rA + al(B_f16T) + al(B_w1b) + al(B_w2R) + al(B_out1P));
  u16* concatP = (u16*)rA;  // overlays phase-1 buffers (dead by then)
  u16*   wtR    = (u16*)alloc(B_wtR);
  u16*   mkT    = (u16*)alloc(B_mkT);
  u16*   logaff = (u16*)alloc(B_logaff);
  u16*   mvb    = (u16*)alloc(B_mvb);
  float* parts  = (float*)alloc(poolFor(S_ro, S_tr));

  // ---- zero padded conv1 image ----
  zfill<<<512, 256, 0, stream>>>((u32*)out1P, (long)(B_out1P / 4));

  // ---- operand prep ----
  convert_bf<<<256, 256, 0, stream>>>(w1, w1b, 65536);
  permute_w<<<1152, 256, 0, stream>>>(w2, w2R, 64, 512);
  permute_w<<<20736, 256, 0, stream>>>(wt, wtR, 768, 768);
  transpose_bf<<<dim3(25, 32, 2), 256, 0, stream>>>(f16, f16T, 1024, 784, 784L*1024, 1024, 0);
  transpose_bf<<<dim3(392, 2, 2), 256, 0, stream>>>(mk, mkT, 64, 12544, 12544L*64, 64, 0);
  convert_bf<<<18816, 256, 0, stream>>>(mv, mvb, 4816896);

  // ---- conv1 (1x1): A=f16T[1568][1024], B=w1b[512][1024], S=8 ----
  gemm256<0><<<dim3(7, 2, 8), 512, DSM, stream>>>(
      f16T, w1b, parts, 1568, 512, 128, 1024, 8, 0, 0, 1568L*512, 0);
  reduce_c1_cl<<<784, 256, 0, stream>>>(parts, out1P, b1, 8);

  // ---- conv2 (3x3 implicit 128-tile): M=64, Cin=512, Ntot=1568, S=18 ----
  conv_glds<<<dim3(1, 13, 18), 256, 0, stream>>>(w2R, out1P, parts, 64, 512, 1568, 256);
  reduceT_qk<<<dim3(2, 25, 2), 256, 0, stream>>>(parts, qkT, b2, 18);

  // ---- logits: M=784, N=12544, K=64 -> bf16, scale 1/8 ----
  gemm_glds<64, 1><<<dim3(7, 98, 2), 256, 0, stream>>>(
      qkT, mkT, logaff, 784, 12544, 64, 64, 1,
      784L*64, 12544L*64, 784L*12544, 0.125f);

  // ---- softmax over memory axis ----
  softmax_inplace<<<1568, 256, 0, stream>>>(logaff);

  // ---- zero concat image, fill h channels ----
  zfill<<<2048, 256, 0, stream>>>((u32*)concatP, (long)(B_concat / 4));
  transT_h<<<dim3(8, 25, 6), 256, 0, stream>>>(hin, concatP);

  // ---- readout: A=logaff[784][12544], B=mvb[1536][12544], per batch ----
  gemm256<0><<<dim3(4, 6, 2 * S_ro), 512, DSM, stream>>>(
      logaff, mvb, parts, 784, 1536, 12544 / S_ro, 12544, S_ro,
      784L*12544, 1536L*12544, 784L*1536, 0);
  reduce_ro_cl<<<2352, 256, 0, stream>>>(parts, concatP, S_ro);

  // ---- transform conv: A=wtR[768][9*768], B=concatP pixels, S_tr ----
  gemm256<1><<<dim3(3, 19, S_tr), 512, DSM, stream>>>(
      wtR, concatP, parts, 768, 4704, 6912 / S_tr, 6912, S_tr,
      0, 0, 768L*4704, 768);

  // ---- fused reduce + gating -> d_out ----
  treduce_gate<<<1176, 256, 0, stream>>>(parts, bt, hin, out, S_tr);
}

// Round 7
// 390.206 us; speedup vs baseline: 1.2290x; 1.0761x over previous
//
#include <hip/hip_runtime.h>

typedef unsigned short u16;
typedef unsigned int u32;
typedef float f32x4v __attribute__((ext_vector_type(4)));
typedef __bf16 bf16x8 __attribute__((ext_vector_type(8)));

#define GAS __attribute__((address_space(1)))
#define LAS __attribute__((address_space(3)))

__device__ __forceinline__ u16 f2bf(float f) {
  u32 u = __builtin_bit_cast(u32, f);
  u32 r = (u + 0x7FFFu + ((u >> 16) & 1u)) >> 16;  // RNE
  return (u16)r;
}
__device__ __forceinline__ float bf2f(u16 h) {
  return __builtin_bit_cast(float, (u32)h << 16);
}
__device__ __forceinline__ void gld_lds16(const void* g, void* l) {
  __builtin_amdgcn_global_load_lds((const GAS void*)g, (LAS void*)l, 16, 0, 0);
}
#define VMCNT(N) asm volatile("s_waitcnt vmcnt(" #N ")" ::: "memory")

// ---------------------------------------------------------------------------
// 256x128 MFMA GEMM, BK=32, 512 thr / 8 waves (4 row x 2 col of 64x64).
// DEPTH-3 circular LDS pipeline (72 KB dynamic LDS -> 2 blocks/CU):
//   stage(t+2) -> vmcnt(6) -> s_barrier -> ds_read+MFMA(t) -> s_barrier
// 3 glds/thread/stage (A:2, B:1). Tail drains vmcnt 3 -> 0.
//   C[m][n] = sum_k A[m][k]*B[n][k]; fp32 partial at Cp + z*strC.
// CONV=1: B is zero-padded channel-last image stack [nImg][900][Cin];
//   B-"rows" are pixels, K = 9*Cin tap-major.
// z = zb*S + s -> batch zb, K-chunk s (k in [s*Kc, min((s+1)*Kc, fullK))).
// ---------------------------------------------------------------------------
template <int CONV>
__global__ __launch_bounds__(512, 4) void gemmRC(
    const u16* __restrict__ A, const u16* __restrict__ B, float* __restrict__ Cp,
    int M, int N, int Kc, int fullK, int S,
    long strA, long strB, long strC, int Cin)
{
  extern __shared__ u16 smem[];       // A: 3 bufs x 8192 u16, B: 3 x 4096 u16
  u16* sA = smem;
  u16* sB = smem + 3 * 8192;
  const int t = threadIdx.x, lane = t & 63, wave = t >> 6;
  const int z = blockIdx.z, zb = z / S, s = z - zb * S;
  const int m0 = blockIdx.x * 256, n0 = blockIdx.y * 128;
  const int kbeg = s * Kc;
  const int kavail = fullK - kbeg;
  const int kc = Kc < kavail ? Kc : kavail;
  const int niter = kc >> 5;

  // staging: A issue q: row = q*128 + (t>>2); B: row = t>>2.
  // source 16B chunk XOR-swizzled: slot (t&3) holds chunk (t&3)^((t>>4)&3).
  const int schunk = ((t & 3) ^ ((t >> 4) & 3)) * 8;
  const u16* Ap[2]; const u16* Bp;
  #pragma unroll
  for (int q = 0; q < 2; ++q) {
    int ra = m0 + q * 128 + (t >> 2); if (ra >= M) ra = M - 1;
    Ap[q] = A + (long)zb * strA + (long)ra * fullK + schunk;
  }
  if constexpr (CONV) {
    int pn = n0 + (t >> 2); if (pn >= N) pn = 0;
    const int img = pn / 784, p = pn - img * 784;
    const int py = p / 28, px = p - py * 28;
    Bp = B + ((long)img * 900 + (py + 1) * 30 + (px + 1)) * Cin + schunk;
  } else {
    int rb = n0 + (t >> 2); if (rb >= N) rb = N - 1;
    Bp = B + (long)zb * strB + (long)rb * fullK + schunk;
  }
  const int ldst = t * 8;   // u16 units: thread t -> (row&127)*32 + slot*8

  auto stage = [&](int buf, int kg) {
    long boff;
    if constexpr (CONV) {
      const int tap = kg / Cin, kcc = kg - tap * Cin;
      boff = (long)((tap / 3 - 1) * 30 + (tap % 3 - 1)) * Cin + kcc;
    } else {
      boff = kg;
    }
    u16* dA = sA + buf * 8192;
    gld_lds16(Ap[0] + kg, &dA[ldst]);
    gld_lds16(Ap[1] + kg, &dA[4096 + ldst]);
    gld_lds16(Bp + boff,  &sB[buf * 4096 + ldst]);
  };

  const int wrow = (wave & 3) * 64, wcol = (wave >> 2) * 64;
  const int lr = lane & 15, hi = lane >> 4;
  const int csw = (hi ^ (lr >> 2)) * 8;   // read slot for source chunk `hi`
  f32x4v acc[4][4] = {};

  for (int p = 0; p < 2 && p < niter; ++p) stage(p, kbeg + p * 32);
  int cur = 0, nxt = 2;
  for (int it = 0; it < niter; ++it) {
    if (it + 2 < niter) {
      stage(nxt, kbeg + (it + 2) * 32);
      VMCNT(6);                         // tile t complete; t+1,t+2 in flight
    } else {
      const int rem = niter - 1 - it;
      if (rem == 1) VMCNT(3); else VMCNT(0);
    }
    __builtin_amdgcn_s_barrier();
    __builtin_amdgcn_sched_barrier(0);
    const u16* cA = sA + cur * 8192;
    const u16* cB = sB + cur * 4096;
    bf16x8 af[4], bf[4];
    #pragma unroll
    for (int m = 0; m < 4; ++m) af[m] = *(const bf16x8*)&cA[(wrow + m*16 + lr) * 32 + csw];
    #pragma unroll
    for (int n = 0; n < 4; ++n) bf[n] = *(const bf16x8*)&cB[(wcol + n*16 + lr) * 32 + csw];
    __builtin_amdgcn_s_setprio(1);
    #pragma unroll
    for (int m = 0; m < 4; ++m)
      #pragma unroll
      for (int n = 0; n < 4; ++n)
        acc[m][n] = __builtin_amdgcn_mfma_f32_16x16x32_bf16(af[m], bf[n], acc[m][n], 0, 0, 0);
    __builtin_amdgcn_s_setprio(0);
    __builtin_amdgcn_sched_barrier(0);
    __builtin_amdgcn_s_barrier();       // W-A-R before next iter's stage
    cur = (cur + 1 == 3) ? 0 : cur + 1;
    nxt = (nxt + 1 == 3) ? 0 : nxt + 1;
  }

  // D: lane l reg r -> row=(l>>4)*4+r, col=l&15
  float* Co = Cp + (long)z * strC;
  const int lq = hi * 4;
  #pragma unroll
  for (int m = 0; m < 4; ++m)
    #pragma unroll
    for (int r = 0; r < 4; ++r) {
      const int row = m0 + wrow + m * 16 + lq + r;
      if (row >= M) continue;
      #pragma unroll
      for (int n = 0; n < 4; ++n) {
        const int col = n0 + wcol + n * 16 + lr;
        if (col < N) Co[(long)row * N + col] = acc[m][n][r];
      }
    }
}

// ---------------------------------------------------------------------------
// 128x128 glds GEMM (logits). Counted-vmcnt, depth-1. OUT=1: bf16 *scale.
// ---------------------------------------------------------------------------
template <int BK, int OUT>
__global__ __launch_bounds__(256) void gemm_glds(
    const u16* __restrict__ A, const u16* __restrict__ B, void* __restrict__ C,
    int M, int N, int Kc, int fullK, int S,
    long strA, long strB, long strC, float scale)
{
  constexpr int CPR = BK / 8;
  constexpr int ISS = BK / 16;
  __shared__ u16 sA[2][128 * BK];
  __shared__ u16 sB[2][128 * BK];
  const int t = threadIdx.x, lane = t & 63, wave = t >> 6;
  const int z = blockIdx.z, zb = z / S, s = z - zb * S;
  const int m0 = blockIdx.x * 128, n0 = blockIdx.y * 128;
  const int kbeg = s * Kc;

  const u16* Aptr[ISS]; const u16* Bptr[ISS]; int lofs[ISS];
  #pragma unroll
  for (int i = 0; i < ISS; ++i) {
    const int tp = i * 256 + t;
    const int r = tp / CPR;
    int c16 = tp % CPR;
    if constexpr (BK == 32) c16 = c16 ^ ((tp >> 4) & 3);
    int ra = m0 + r; if (ra >= M) ra = M - 1;
    int rb = n0 + r; if (rb >= N) rb = N - 1;
    Aptr[i] = A + (long)zb * strA + (long)ra * fullK + kbeg + c16 * 8;
    Bptr[i] = B + (long)zb * strB + (long)rb * fullK + kbeg + c16 * 8;
    lofs[i] = (i * 256 + (wave << 6)) * 8;
  }
  auto stage = [&](int buf, int k0) {
    #pragma unroll
    for (int i = 0; i < ISS; ++i) {
      gld_lds16(Aptr[i] + k0, &sA[buf][lofs[i]]);
      gld_lds16(Bptr[i] + k0, &sB[buf][lofs[i]]);
    }
  };

  const int wr = (wave >> 1) * 64, wc = (wave & 1) * 64;
  const int lr = lane & 15, hi = lane >> 4;
  f32x4v acc[4][4] = {};
  const int niter = Kc / BK;

  stage(0, 0);
  for (int it = 0; it < niter; ++it) {
    const int cur = it & 1;
    if (it + 1 < niter) {
      stage(cur ^ 1, (it + 1) * BK);
      if constexpr (ISS == 2) VMCNT(4); else VMCNT(8);
    } else {
      VMCNT(0);
    }
    __builtin_amdgcn_s_barrier();
    __builtin_amdgcn_sched_barrier(0);
    #pragma unroll
    for (int kk = 0; kk < BK; kk += 32) {
      int lk = kk + hi * 8;
      if constexpr (BK == 32) lk = kk + ((hi ^ (lr >> 2)) * 8);
      bf16x8 af[4], bv[4];
      #pragma unroll
      for (int i = 0; i < 4; ++i) af[i] = *(const bf16x8*)&sA[cur][(wr + i*16 + lr) * BK + lk];
      #pragma unroll
      for (int j = 0; j < 4; ++j) bv[j] = *(const bf16x8*)&sB[cur][(wc + j*16 + lr) * BK + lk];
      __builtin_amdgcn_s_setprio(1);
      #pragma unroll
      for (int i = 0; i < 4; ++i)
        #pragma unroll
        for (int j = 0; j < 4; ++j)
          acc[i][j] = __builtin_amdgcn_mfma_f32_16x16x32_bf16(af[i], bv[j], acc[i][j], 0, 0, 0);
      __builtin_amdgcn_s_setprio(0);
    }
    __builtin_amdgcn_sched_barrier(0);
    __builtin_amdgcn_s_barrier();
  }

  const int lq = hi * 4;
  if constexpr (OUT == 0) {
    float* Cp = (float*)C + (long)z * strC;
    #pragma unroll
    for (int i = 0; i < 4; ++i)
      #pragma unroll
      for (int r = 0; r < 4; ++r) {
        const int row = m0 + wr + i*16 + lq + r;
        if (row >= M) continue;
        #pragma unroll
        for (int j = 0; j < 4; ++j) {
          const int col = n0 + wc + j*16 + lr;
          if (col < N) Cp[(long)row * N + col] = acc[i][j][r];
        }
      }
  } else {
    u16* Cp = (u16*)C + (long)zb * strC;
    #pragma unroll
    for (int i = 0; i < 4; ++i)
      #pragma unroll
      for (int r = 0; r < 4; ++r) {
        const int row = m0 + wr + i*16 + lq + r;
        if (row >= M) continue;
        #pragma unroll
        for (int j = 0; j < 4; ++j) {
          const int col = n0 + wc + j*16 + lr;
          if (col < N) Cp[(long)row * N + col] = f2bf(acc[i][j][r] * scale);
        }
      }
  }
}

// ---------------------------------------------------------------------------
// 128x128 implicit-conv (conv2: M=64). Counted-vmcnt depth-1.
// ---------------------------------------------------------------------------
__global__ __launch_bounds__(256) void conv_glds(
    const u16* __restrict__ Wt, const u16* __restrict__ imgP,
    float* __restrict__ Cp, int M, int Cin, int Ntot, int Kc)
{
  __shared__ u16 sA[2][128 * 32];
  __shared__ u16 sB[2][128 * 32];
  const int t = threadIdx.x, lane = t & 63, wave = t >> 6;
  const int z = blockIdx.z;
  const int m0 = blockIdx.x * 128, n0 = blockIdx.y * 128;
  const int kbeg = z * Kc;

  const u16* Aptr[2]; const u16* Bptr[2]; int lofs[2];
  #pragma unroll
  for (int i = 0; i < 2; ++i) {
    const int tp = i * 256 + t;
    const int r = tp >> 2;
    const int c16 = (tp & 3) ^ ((tp >> 4) & 3);
    int ra = m0 + r; if (ra >= M) ra = M - 1;
    int pn = n0 + r; if (pn >= Ntot) pn = 0;
    const int img = pn / 784, p = pn - img * 784;
    const int py = p / 28, px = p - py * 28;
    Aptr[i] = Wt + (long)ra * (9 * Cin) + c16 * 8;
    Bptr[i] = imgP + ((long)img * 900 + (py + 1) * 30 + (px + 1)) * Cin + c16 * 8;
    lofs[i] = (i * 256 + (wave << 6)) * 8;
  }
  auto stage = [&](int buf, int kg) {
    const int tap = kg / Cin, kc = kg - tap * Cin;
    const long off = (long)((tap / 3 - 1) * 30 + (tap % 3 - 1)) * Cin + kc;
    #pragma unroll
    for (int i = 0; i < 2; ++i) {
      gld_lds16(Aptr[i] + kg, &sA[buf][lofs[i]]);
      gld_lds16(Bptr[i] + off, &sB[buf][lofs[i]]);
    }
  };

  const int wr = (wave >> 1) * 64, wc = (wave & 1) * 64;
  const int lr = lane & 15, hi = lane >> 4;
  const int csw = (hi ^ (lr >> 2)) * 8;
  f32x4v acc[4][4] = {};
  const int niter = Kc >> 5;

  stage(0, kbeg);
  for (int it = 0; it < niter; ++it) {
    const int cur = it & 1;
    if (it + 1 < niter) {
      stage(cur ^ 1, kbeg + (it + 1) * 32);
      VMCNT(4);
    } else {
      VMCNT(0);
    }
    __builtin_amdgcn_s_barrier();
    __builtin_amdgcn_sched_barrier(0);
    bf16x8 af[4], bv[4];
    #pragma unroll
    for (int i = 0; i < 4; ++i) af[i] = *(const bf16x8*)&sA[cur][(wr + i*16 + lr) * 32 + csw];
    #pragma unroll
    for (int j = 0; j < 4; ++j) bv[j] = *(const bf16x8*)&sB[cur][(wc + j*16 + lr) * 32 + csw];
    __builtin_amdgcn_s_setprio(1);
    #pragma unroll
    for (int i = 0; i < 4; ++i)
      #pragma unroll
      for (int j = 0; j < 4; ++j)
        acc[i][j] = __builtin_amdgcn_mfma_f32_16x16x32_bf16(af[i], bv[j], acc[i][j], 0, 0, 0);
    __builtin_amdgcn_s_setprio(0);
    __builtin_amdgcn_sched_barrier(0);
    __builtin_amdgcn_s_barrier();
  }

  float* Co = Cp + (long)z * M * Ntot;
  const int lq = hi * 4;
  #pragma unroll
  for (int i = 0; i < 4; ++i)
    #pragma unroll
    for (int r = 0; r < 4; ++r) {
      const int row = m0 + wr + i*16 + lq + r;
      if (row >= M) continue;
      #pragma unroll
      for (int j = 0; j < 4; ++j) {
        const int col = n0 + wc + j*16 + lr;
        if (col < Ntot) Co[(long)row * Ntot + col] = acc[i][j][r];
      }
    }
}

// ---------------------------------------------------------------------------
// Helpers
// ---------------------------------------------------------------------------
__global__ __launch_bounds__(256) void transpose_bf(
    const float* __restrict__ in, u16* __restrict__ out,
    int R, int C, long strOutZ, int ldOut, int colOff)
{
  __shared__ float tile[32][33];
  in  += (long)blockIdx.z * R * C;
  out += (long)blockIdx.z * strOutZ;
  const int c0 = blockIdx.x * 32, r0 = blockIdx.y * 32;
  const int tx = threadIdx.x & 31, ty = threadIdx.x >> 5;
  for (int i = ty; i < 32; i += 8) {
    const int r = r0 + i, c = c0 + tx;
    tile[i][tx] = (r < R && c < C) ? in[(long)r * C + c] : 0.0f;
  }
  __syncthreads();
  for (int i = ty; i < 32; i += 8) {
    const int r = r0 + tx, c = c0 + i;
    if (c < C && r < R)
      out[(long)c * ldOut + colOff + r] = f2bf(tile[tx][i]);
  }
}

__global__ __launch_bounds__(256) void convert_bf(
    const float* __restrict__ in, u16* __restrict__ out, long n8)
{
  const long i = (long)blockIdx.x * 256 + threadIdx.x;
  if (i >= n8) return;
  const float4* p = (const float4*)in + i * 2;
  const float4 a = p[0], b = p[1];
  u16 o[8] = {f2bf(a.x), f2bf(a.y), f2bf(a.z), f2bf(a.w),
              f2bf(b.x), f2bf(b.y), f2bf(b.z), f2bf(b.w)};
  ((uint4*)out)[i] = *(uint4*)o;
}

__global__ __launch_bounds__(256) void permute_w(
    const float* __restrict__ src, u16* __restrict__ dst, int M, int Cin)
{
  const long total = (long)M * 9 * Cin;
  const long idx = (long)blockIdx.x * 256 + threadIdx.x;
  if (idx >= total) return;
  const int c = (int)(idx % Cin);
  const int tap = (int)((idx / Cin) % 9);
  const int m = (int)(idx / ((long)9 * Cin));
  dst[idx] = f2bf(src[((long)m * Cin + c) * 9 + tap]);
}

__global__ __launch_bounds__(256) void zfill(u32* __restrict__ p, long n) {
  const long stride = (long)gridDim.x * 256;
  for (long i = (long)blockIdx.x * 256 + threadIdx.x; i < n; i += stride) p[i] = 0;
}

// ---------------------------------------------------------------------------
// Reduce kernels
// ---------------------------------------------------------------------------
// conv1: parts[S][1568][512] (pixel-major) -> out1P[b][900pad][512] bf16 +b1
__global__ __launch_bounds__(256) void reduce_c1_cl(
    const float* __restrict__ parts, u16* __restrict__ dst,
    const float* __restrict__ bias, int S)
{
  const long idx = (long)blockIdx.x * 256 + threadIdx.x;
  if (idx >= 1568L * 128) return;
  const int c4 = (int)(idx & 127), p = (int)(idx >> 7);
  const int c = c4 * 4;
  f32x4v sum = *(const f32x4v*)&bias[c];
  for (int s = 0; s < S; ++s)
    sum += *(const f32x4v*)&parts[((long)s * 1568 + p) * 512 + c];
  const int im = p / 784, q = p - im * 784;
  const int qpad = (q / 28 + 1) * 30 + (q % 28 + 1);
  u16 o[4] = {f2bf(sum[0]), f2bf(sum[1]), f2bf(sum[2]), f2bf(sum[3])};
  *(uint2*)&dst[((long)im * 900 + qpad) * 512 + c] = *(uint2*)o;
}

// readout: parts[(b*S+s)][1536][784] (channel-major) -> concatP[b*3+n][900pad][768]
__global__ __launch_bounds__(256) void reduceT_ro(
    const float* __restrict__ parts, u16* __restrict__ dst, int S)
{
  __shared__ float tile[32][33];
  const int b = blockIdx.z, c0 = blockIdx.x * 32, p0 = blockIdx.y * 32;
  const int tx = threadIdx.x & 31, ty = threadIdx.x >> 5;
  for (int i = ty; i < 32; i += 8) {
    const int pc = min(p0 + tx, 783);
    float s = 0;
    for (int k = 0; k < S; ++k)
      s += parts[((long)(b * S + k) * 1536 + c0 + i) * 784 + pc];
    tile[i][tx] = s;
  }
  __syncthreads();
  for (int i = ty; i < 32; i += 8) {
    const int p = p0 + i, c = c0 + tx;
    if (p < 784) {
      const int n = c >> 9, cc = c & 511;
      const int qpad = (p / 28 + 1) * 30 + (p % 28 + 1);
      dst[((long)(b * 3 + n) * 900 + qpad) * 768 + cc] = f2bf(tile[tx][i]);
    }
  }
}

// conv2: parts[S][64][1568] -> qkT[b][784][64] (+b2)
__global__ __launch_bounds__(256) void reduceT_qk(
    const float* __restrict__ parts, u16* __restrict__ dst,
    const float* __restrict__ bias, int S)
{
  __shared__ float tile[32][33];
  const int b = blockIdx.z, c0 = blockIdx.x * 32, p0 = blockIdx.y * 32;
  const int tx = threadIdx.x & 31, ty = threadIdx.x >> 5;
  for (int i = ty; i < 32; i += 8) {
    const int pc = min(p0 + tx, 783);
    const long base = (long)(c0 + i) * 1568 + b * 784 + pc;
    float s = 0;
    for (int k = 0; k < S; ++k) s += parts[(long)k * 64 * 1568 + base];
    tile[i][tx] = s;
  }
  __syncthreads();
  for (int i = ty; i < 32; i += 8) {
    const int p = p0 + i, c = c0 + tx;
    if (p < 784)
      dst[((long)b * 784 + p) * 64 + c] = f2bf(tile[tx][i] + bias[c]);
  }
}

__global__ __launch_bounds__(256) void transT_h(
    const float* __restrict__ h, u16* __restrict__ dst)
{
  __shared__ float tile[32][33];
  const int zimg = blockIdx.z, c0 = blockIdx.x * 32, p0 = blockIdx.y * 32;
  const int tx = threadIdx.x & 31, ty = threadIdx.x >> 5;
  for (int i = ty; i < 32; i += 8) {
    const int pc = min(p0 + tx, 783);
    tile[i][tx] = h[((long)zimg * 256 + c0 + i) * 784 + pc];
  }
  __syncthreads();
  for (int i = ty; i < 32; i += 8) {
    const int p = p0 + i, c = c0 + tx;
    if (p < 784) {
      const int qpad = (p / 28 + 1) * 30 + (p % 28 + 1);
      dst[((long)zimg * 900 + qpad) * 768 + 512 + c] = f2bf(tile[tx][i]);
    }
  }
}

// ---------------------------------------------------------------------------
// In-place softmax over rows of 12544 bf16 (one block per row)
// ---------------------------------------------------------------------------
__global__ __launch_bounds__(256) void softmax_inplace(u16* __restrict__ buf)
{
  u16* ptr = buf + (long)blockIdx.x * 12544;
  uint4* p4 = (uint4*)ptr;
  const int t = threadIdx.x;
  __shared__ float red[4];
  float mx = -3.0e38f;
  for (int v = t; v < 1568; v += 256) {
    uint4 u = p4[v];
    const u32 w[4] = {u.x, u.y, u.z, u.w};
    #pragma unroll
    for (int q = 0; q < 4; ++q) {
      mx = fmaxf(mx, bf2f((u16)(w[q] & 0xFFFFu)));
      mx = fmaxf(mx, bf2f((u16)(w[q] >> 16)));
    }
  }
  #pragma unroll
  for (int o = 32; o > 0; o >>= 1) mx = fmaxf(mx, __shfl_xor(mx, o));
  if ((t & 63) == 0) red[t >> 6] = mx;
  __syncthreads();
  mx = fmaxf(fmaxf(red[0], red[1]), fmaxf(red[2], red[3]));

  float s = 0.0f;
  for (int v = t; v < 1568; v += 256) {
    uint4 u = p4[v];
    const u32 w[4] = {u.x, u.y, u.z, u.w};
    #pragma unroll
    for (int q = 0; q < 4; ++q) {
      s += __expf(bf2f((u16)(w[q] & 0xFFFFu)) - mx);
      s += __expf(bf2f((u16)(w[q] >> 16)) - mx);
    }
  }
  #pragma unroll
  for (int o = 32; o > 0; o >>= 1) s += __shfl_xor(s, o);
  __syncthreads();
  if ((t & 63) == 0) red[t >> 6] = s;
  __syncthreads();
  const float inv = 1.0f / (red[0] + red[1] + red[2] + red[3]);

  for (int v = t; v < 1568; v += 256) {
    uint4 u = p4[v];
    u32 w[4] = {u.x, u.y, u.z, u.w};
    #pragma unroll
    for (int q = 0; q < 4; ++q) {
      const float a = __expf(bf2f((u16)(w[q] & 0xFFFFu)) - mx) * inv;
      const float b = __expf(bf2f((u16)(w[q] >> 16)) - mx) * inv;
      w[q] = (u32)f2bf(a) | ((u32)f2bf(b) << 16);
    }
    p4[v] = make_uint4(w[0], w[1], w[2], w[3]);
  }
}

// ---------------------------------------------------------------------------
// Fused transform-reduce + gating. parts: [S][768][4704] fp32 (channel-major)
// ---------------------------------------------------------------------------
__global__ __launch_bounds__(256) void treduce_gate(
    const float* __restrict__ parts, const float* __restrict__ bt,
    const float* __restrict__ h, float* __restrict__ out, int S)
{
  const long i = (long)blockIdx.x * 256 + threadIdx.x;
  if (i >= 6L * 256 * 196) return;
  const int p4 = (int)(i % 196);
  const int rest = (int)(i / 196);
  const int cs = rest % 256, im = rest / 256;
  const long slice4 = (768L * 4704) >> 2;
  const long colBase = ((long)im * 784) >> 2;
  f32x4v F = {0,0,0,0}, U = {0,0,0,0}, NV = {0,0,0,0};
  for (int s = 0; s < S; ++s) {
    const f32x4v* P = (const f32x4v*)parts + (long)s * slice4;
    F  += P[(((long)cs        * 4704) >> 2) + colBase + p4];
    U  += P[(((long)(256 + cs) * 4704) >> 2) + colBase + p4];
    NV += P[(((long)(512 + cs) * 4704) >> 2) + colBase + p4];
  }
  const float bF = bt[cs], bU = bt[256 + cs], bN = bt[512 + cs];
  const f32x4v hv = ((const f32x4v*)h)[((long)(im * 256 + cs) * 784 >> 2) + p4];
  f32x4v o;
  #pragma unroll
  for (int q = 0; q < 4; ++q) {
    const float f = F[q] + bF, u = U[q] + bU, nv = NV[q] + bN;
    const float sf = 1.0f / (1.0f + __expf(-f));
    const float su = 1.0f / (1.0f + __expf(-u));
    const float e2 = __expf(2.0f * nv);
    const float tv = (e2 - 1.0f) / (e2 + 1.0f);
    o[q] = sf * hv[q] * (1.0f - su) + su * tv;
  }
  ((f32x4v*)out)[((long)(im * 256 + cs) * 784 >> 2) + p4] = o;
}

__global__ __launch_bounds__(256) void fill_sentinel(float* p, long n) {
  const long i = (long)blockIdx.x * 256 + threadIdx.x;
  if (i < n) p[i] = 12345.0f;
}

// ---------------------------------------------------------------------------
extern "C" void kernel_launch(void* const* d_in, const int* in_sizes, int n_in,
                              void* d_out, int out_size, void* d_ws, size_t ws_size,
                              hipStream_t stream) {
  const float* f16 = (const float*)d_in[0];
  const float* mk  = (const float*)d_in[1];
  const float* mv  = (const float*)d_in[2];
  const float* hin = (const float*)d_in[3];
  const float* w1  = (const float*)d_in[4];
  const float* b1  = (const float*)d_in[5];
  const float* w2  = (const float*)d_in[6];
  const float* b2  = (const float*)d_in[7];
  const float* wt  = (const float*)d_in[8];
  const float* bt  = (const float*)d_in[9];
  float* out = (float*)d_out;

  // 72 KB dynamic LDS for gemmRC (host-side, capture-safe)
  (void)hipFuncSetAttribute((const void*)gemmRC<0>,
                            hipFuncAttributeMaxDynamicSharedMemorySize, 73728);
  (void)hipFuncSetAttribute((const void*)gemmRC<1>,
                            hipFuncAttributeMaxDynamicSharedMemorySize, 73728);
  constexpr unsigned DSM = 73728;

  const size_t B_f16T   = 2UL*784*1024*2;
  const size_t B_w1b    = 512UL*1024*2;
  const size_t B_w2R    = 64UL*4608*2;
  const size_t B_out1P  = 2UL*900*512*2;
  const size_t B_qkT    = 2UL*784*64*2;
  const size_t B_concat = 6UL*900*768*2;
  const size_t B_wtR    = 768UL*6912*2;
  const size_t B_mkT    = 2UL*12544*64*2;
  const size_t B_logaff = 2UL*784*12544*2;
  const size_t B_mvb    = 38535168UL*2;
  auto al = [](size_t x) { return (x + 255) & ~(size_t)255; };
  auto kcFor = [](int K, int S) { return ((K + S - 1) / S + 31) & ~31; };

  const size_t phase1 = al(B_f16T) + al(B_w1b) + al(B_w2R) + al(B_out1P) + al(B_qkT);
  const size_t regionA = phase1 > al(B_concat) ? phase1 : al(B_concat);

  auto poolFor = [&](int S_ro, int S_tr) -> size_t {
    size_t p1 = 8UL*1568*512*4, p2 = 18UL*64*1568*4;
    size_t pr = (size_t)(2*S_ro)*1536*784*4, pt = (size_t)S_tr*768*4704*4;
    size_t m = p1; if (p2 > m) m = p2; if (pr > m) m = pr; if (pt > m) m = pt;
    return m;
  };
  const size_t fixed = regionA + al(B_wtR) + al(B_mkT) + al(B_logaff) + al(B_mvb);

  int S_ro = 6, S_tr = 4;   // readout grid 504 (2 blk/CU), transform 444
  if (fixed + poolFor(S_ro, S_tr) > ws_size) { S_ro = 3; S_tr = 2; }
  if (fixed + poolFor(S_ro, S_tr) > ws_size) {
    fill_sentinel<<<4704, 256, 0, stream>>>(out, (long)out_size);
    return;
  }
  const int Kc_ro = kcFor(12544, S_ro);   // 2112 (S=6) / 4192 (S=3)
  const int Kc_tr = kcFor(6912, S_tr);    // 1728 (S=4) / 3456 (S=2)

  char* base = (char*)d_ws;
  size_t off = 0;
  auto alloc = [&](size_t bytes) -> char* { char* p = base + off; off += al(bytes); return p; };
  char* rA = alloc(regionA);
  u16* f16T   = (u16*)rA;
  u16* w1b    = (u16*)(rA + al(B_f16T));
  u16* w2R    = (u16*)(rA + al(B_f16T) + al(B_w1b));
  u16* out1P  = (u16*)(rA + al(B_f16T) + al(B_w1b) + al(B_w2R));
  u16* qkT    = (u16*)(rA + al(B_f16T) + al(B_w1b) + al(B_w2R) + al(B_out1P));
  u16* concatP = (u16*)rA;  // overlays phase-1 buffers (dead by then)
  u16*   wtR    = (u16*)alloc(B_wtR);
  u16*   mkT    = (u16*)alloc(B_mkT);
  u16*   logaff = (u16*)alloc(B_logaff);
  u16*   mvb    = (u16*)alloc(B_mvb);
  float* parts  = (float*)alloc(poolFor(S_ro, S_tr));

  // ---- zero padded conv1 image ----
  zfill<<<512, 256, 0, stream>>>((u32*)out1P, (long)(B_out1P / 4));

  // ---- operand prep ----
  convert_bf<<<256, 256, 0, stream>>>(w1, w1b, 65536);
  permute_w<<<1152, 256, 0, stream>>>(w2, w2R, 64, 512);
  permute_w<<<20736, 256, 0, stream>>>(wt, wtR, 768, 768);
  transpose_bf<<<dim3(25, 32, 2), 256, 0, stream>>>(f16, f16T, 1024, 784, 784L*1024, 1024, 0);
  transpose_bf<<<dim3(392, 2, 2), 256, 0, stream>>>(mk, mkT, 64, 12544, 12544L*64, 64, 0);
  convert_bf<<<18816, 256, 0, stream>>>(mv, mvb, 4816896);

  // ---- conv1 (1x1): A=f16T[1568][1024] (pixel rows), B=w1b[512][1024], S=8 ----
  gemmRC<0><<<dim3(7, 4, 8), 512, DSM, stream>>>(
      f16T, w1b, parts, 1568, 512, 128, 1024, 8, 0, 0, 1568L*512, 0);
  reduce_c1_cl<<<784, 256, 0, stream>>>(parts, out1P, b1, 8);

  // ---- conv2 (3x3 implicit 128-tile): M=64, Cin=512, Ntot=1568, S=18 ----
  conv_glds<<<dim3(1, 13, 18), 256, 0, stream>>>(w2R, out1P, parts, 64, 512, 1568, 256);
  reduceT_qk<<<dim3(2, 25, 2), 256, 0, stream>>>(parts, qkT, b2, 18);

  // ---- logits: M=784, N=12544, K=64 -> bf16, scale 1/8 ----
  gemm_glds<64, 1><<<dim3(7, 98, 2), 256, 0, stream>>>(
      qkT, mkT, logaff, 784, 12544, 64, 64, 1,
      784L*64, 12544L*64, 784L*12544, 0.125f);

  // ---- softmax over memory axis ----
  softmax_inplace<<<1568, 256, 0, stream>>>(logaff);

  // ---- zero concat image, fill h channels ----
  zfill<<<2048, 256, 0, stream>>>((u32*)concatP, (long)(B_concat / 4));
  transT_h<<<dim3(8, 25, 6), 256, 0, stream>>>(hin, concatP);

  // ---- readout: A=mvb[1536][12544] (M exact), B=logaff[784][12544], S_ro ----
  gemmRC<0><<<dim3(6, 7, 2 * S_ro), 512, DSM, stream>>>(
      mvb, logaff, parts, 1536, 784, Kc_ro, 12544, S_ro,
      1536L*12544, 784L*12544, 1536L*784, 0);
  reduceT_ro<<<dim3(48, 25, 2), 256, 0, stream>>>(parts, concatP, S_ro);

  // ---- transform conv: A=wtR[768][9*768] (M exact), B=concatP pixels, S_tr ----
  gemmRC<1><<<dim3(3, 37, S_tr), 512, DSM, stream>>>(
      wtR, concatP, parts, 768, 4704, Kc_tr, 6912, S_tr,
      0, 0, 768L*4704, 768);

  // ---- fused reduce + gating -> d_out ----
  treduce_gate<<<1176, 256, 0, stream>>>(parts, bt, hin, out, S_tr);
}

// Round 8
// 376.448 us; speedup vs baseline: 1.2739x; 1.0365x over previous
//
#include <hip/hip_runtime.h>

typedef unsigned short u16;
typedef unsigned int u32;
typedef float f32x4v __attribute__((ext_vector_type(4)));
typedef __bf16 bf16x8 __attribute__((ext_vector_type(8)));

#define GAS __attribute__((address_space(1)))
#define LAS __attribute__((address_space(3)))

__device__ __forceinline__ u16 f2bf(float f) {
  u32 u = __builtin_bit_cast(u32, f);
  u32 r = (u + 0x7FFFu + ((u >> 16) & 1u)) >> 16;  // RNE
  return (u16)r;
}
__device__ __forceinline__ float bf2f(u16 h) {
  return __builtin_bit_cast(float, (u32)h << 16);
}
__device__ __forceinline__ void gld_lds16(const void* g, void* l) {
  __builtin_amdgcn_global_load_lds((const GAS void*)g, (LAS void*)l, 16, 0, 0);
}
#define VMCNT(N) asm volatile("s_waitcnt vmcnt(" #N ")" ::: "memory")

// ---------------------------------------------------------------------------
// 256x128 MFMA GEMM, BK=32, 512 thr / 8 waves, depth-3 circular pipeline
// (72 KB dynamic LDS, 2 blocks/CU), counted vmcnt(6).
// 1D grid + XCD-chunked remap (T1): launch index i -> L=(i&7)*cpx+(i>>3);
// L decoded y-fastest so all gy N-tiles sharing an A-tile(x,z) run on ONE
// XCD -> A-tile is fetched into that XCD's L2 once. Pad grid to x8; dummy
// blocks exit before any barrier.
//   C[m][n] = sum_k A[m][k]*B[n][k]; fp32 partial at Cp + z*strC.
// CONV=1: B is zero-padded channel-last image stack [nImg][900][Cin].
// z = zb*S + s -> batch zb, K-chunk s.
// ---------------------------------------------------------------------------
template <int CONV>
__global__ __launch_bounds__(512, 4) void gemmRC(
    const u16* __restrict__ A, const u16* __restrict__ B, float* __restrict__ Cp,
    int M, int N, int Kc, int fullK, int S,
    long strA, long strB, long strC, int Cin, int gx, int gy, int nwg)
{
  const int cpx = (int)gridDim.x >> 3;
  const int L = ((int)blockIdx.x & 7) * cpx + ((int)blockIdx.x >> 3);
  if (L >= nwg) return;
  const int by = L % gy;
  const int rest = L / gy;
  const int bx = rest % gx;
  const int z = rest / gx;

  extern __shared__ u16 smem[];       // A: 3 bufs x 8192 u16, B: 3 x 4096 u16
  u16* sA = smem;
  u16* sB = smem + 3 * 8192;
  const int t = threadIdx.x, lane = t & 63, wave = t >> 6;
  const int zb = z / S, s = z - zb * S;
  const int m0 = bx * 256, n0 = by * 128;
  const int kbeg = s * Kc;
  const int kavail = fullK - kbeg;
  const int kc = Kc < kavail ? Kc : kavail;
  const int niter = kc >> 5;

  // staging: A issue q: row = q*128 + (t>>2); B: row = t>>2.
  // source 16B chunk XOR-swizzled: slot (t&3) holds chunk (t&3)^((t>>4)&3).
  const int schunk = ((t & 3) ^ ((t >> 4) & 3)) * 8;
  const u16* Ap[2]; const u16* Bp;
  #pragma unroll
  for (int q = 0; q < 2; ++q) {
    int ra = m0 + q * 128 + (t >> 2); if (ra >= M) ra = M - 1;
    Ap[q] = A + (long)zb * strA + (long)ra * fullK + schunk;
  }
  if constexpr (CONV) {
    int pn = n0 + (t >> 2); if (pn >= N) pn = 0;
    const int img = pn / 784, p = pn - img * 784;
    const int py = p / 28, px = p - py * 28;
    Bp = B + ((long)img * 900 + (py + 1) * 30 + (px + 1)) * Cin + schunk;
  } else {
    int rb = n0 + (t >> 2); if (rb >= N) rb = N - 1;
    Bp = B + (long)zb * strB + (long)rb * fullK + schunk;
  }
  const int ldst = t * 8;   // u16 units

  auto stage = [&](int buf, int kg) {
    long boff;
    if constexpr (CONV) {
      const int tap = kg / Cin, kcc = kg - tap * Cin;
      boff = (long)((tap / 3 - 1) * 30 + (tap % 3 - 1)) * Cin + kcc;
    } else {
      boff = kg;
    }
    u16* dA = sA + buf * 8192;
    gld_lds16(Ap[0] + kg, &dA[ldst]);
    gld_lds16(Ap[1] + kg, &dA[4096 + ldst]);
    gld_lds16(Bp + boff,  &sB[buf * 4096 + ldst]);
  };

  const int wrow = (wave & 3) * 64, wcol = (wave >> 2) * 64;
  const int lr = lane & 15, hi = lane >> 4;
  const int csw = (hi ^ (lr >> 2)) * 8;
  f32x4v acc[4][4] = {};

  for (int p = 0; p < 2 && p < niter; ++p) stage(p, kbeg + p * 32);
  int cur = 0, nxt = 2;
  for (int it = 0; it < niter; ++it) {
    if (it + 2 < niter) {
      stage(nxt, kbeg + (it + 2) * 32);
      VMCNT(6);                         // tile t done; t+1,t+2 in flight
    } else {
      const int rem = niter - 1 - it;
      if (rem == 1) VMCNT(3); else VMCNT(0);
    }
    __builtin_amdgcn_s_barrier();
    __builtin_amdgcn_sched_barrier(0);
    const u16* cA = sA + cur * 8192;
    const u16* cB = sB + cur * 4096;
    bf16x8 af[4], bf[4];
    #pragma unroll
    for (int m = 0; m < 4; ++m) af[m] = *(const bf16x8*)&cA[(wrow + m*16 + lr) * 32 + csw];
    #pragma unroll
    for (int n = 0; n < 4; ++n) bf[n] = *(const bf16x8*)&cB[(wcol + n*16 + lr) * 32 + csw];
    __builtin_amdgcn_s_setprio(1);
    #pragma unroll
    for (int m = 0; m < 4; ++m)
      #pragma unroll
      for (int n = 0; n < 4; ++n)
        acc[m][n] = __builtin_amdgcn_mfma_f32_16x16x32_bf16(af[m], bf[n], acc[m][n], 0, 0, 0);
    __builtin_amdgcn_s_setprio(0);
    __builtin_amdgcn_sched_barrier(0);
    __builtin_amdgcn_s_barrier();       // W-A-R before next iter's stage
    cur = (cur + 1 == 3) ? 0 : cur + 1;
    nxt = (nxt + 1 == 3) ? 0 : nxt + 1;
  }

  // D: lane l reg r -> row=(l>>4)*4+r, col=l&15
  float* Co = Cp + (long)z * strC;
  const int lq = hi * 4;
  #pragma unroll
  for (int m = 0; m < 4; ++m)
    #pragma unroll
    for (int r = 0; r < 4; ++r) {
      const int row = m0 + wrow + m * 16 + lq + r;
      if (row >= M) continue;
      #pragma unroll
      for (int n = 0; n < 4; ++n) {
        const int col = n0 + wcol + n * 16 + lr;
        if (col < N) Co[(long)row * N + col] = acc[m][n][r];
      }
    }
}

// ---------------------------------------------------------------------------
// 128x128 glds GEMM (logits). Counted-vmcnt, depth-1. OUT=1: bf16 *scale.
// ---------------------------------------------------------------------------
template <int BK, int OUT>
__global__ __launch_bounds__(256) void gemm_glds(
    const u16* __restrict__ A, const u16* __restrict__ B, void* __restrict__ C,
    int M, int N, int Kc, int fullK, int S,
    long strA, long strB, long strC, float scale)
{
  constexpr int CPR = BK / 8;
  constexpr int ISS = BK / 16;
  __shared__ u16 sA[2][128 * BK];
  __shared__ u16 sB[2][128 * BK];
  const int t = threadIdx.x, lane = t & 63, wave = t >> 6;
  const int z = blockIdx.z, zb = z / S, s = z - zb * S;
  const int m0 = blockIdx.x * 128, n0 = blockIdx.y * 128;
  const int kbeg = s * Kc;

  const u16* Aptr[ISS]; const u16* Bptr[ISS]; int lofs[ISS];
  #pragma unroll
  for (int i = 0; i < ISS; ++i) {
    const int tp = i * 256 + t;
    const int r = tp / CPR;
    int c16 = tp % CPR;
    if constexpr (BK == 32) c16 = c16 ^ ((tp >> 4) & 3);
    int ra = m0 + r; if (ra >= M) ra = M - 1;
    int rb = n0 + r; if (rb >= N) rb = N - 1;
    Aptr[i] = A + (long)zb * strA + (long)ra * fullK + kbeg + c16 * 8;
    Bptr[i] = B + (long)zb * strB + (long)rb * fullK + kbeg + c16 * 8;
    lofs[i] = (i * 256 + (wave << 6)) * 8;
  }
  auto stage = [&](int buf, int k0) {
    #pragma unroll
    for (int i = 0; i < ISS; ++i) {
      gld_lds16(Aptr[i] + k0, &sA[buf][lofs[i]]);
      gld_lds16(Bptr[i] + k0, &sB[buf][lofs[i]]);
    }
  };

  const int wr = (wave >> 1) * 64, wc = (wave & 1) * 64;
  const int lr = lane & 15, hi = lane >> 4;
  f32x4v acc[4][4] = {};
  const int niter = Kc / BK;

  stage(0, 0);
  for (int it = 0; it < niter; ++it) {
    const int cur = it & 1;
    if (it + 1 < niter) {
      stage(cur ^ 1, (it + 1) * BK);
      if constexpr (ISS == 2) VMCNT(4); else VMCNT(8);
    } else {
      VMCNT(0);
    }
    __builtin_amdgcn_s_barrier();
    __builtin_amdgcn_sched_barrier(0);
    #pragma unroll
    for (int kk = 0; kk < BK; kk += 32) {
      int lk = kk + hi * 8;
      if constexpr (BK == 32) lk = kk + ((hi ^ (lr >> 2)) * 8);
      bf16x8 af[4], bv[4];
      #pragma unroll
      for (int i = 0; i < 4; ++i) af[i] = *(const bf16x8*)&sA[cur][(wr + i*16 + lr) * BK + lk];
      #pragma unroll
      for (int j = 0; j < 4; ++j) bv[j] = *(const bf16x8*)&sB[cur][(wc + j*16 + lr) * BK + lk];
      __builtin_amdgcn_s_setprio(1);
      #pragma unroll
      for (int i = 0; i < 4; ++i)
        #pragma unroll
        for (int j = 0; j < 4; ++j)
          acc[i][j] = __builtin_amdgcn_mfma_f32_16x16x32_bf16(af[i], bv[j], acc[i][j], 0, 0, 0);
      __builtin_amdgcn_s_setprio(0);
    }
    __builtin_amdgcn_sched_barrier(0);
    __builtin_amdgcn_s_barrier();
  }

  const int lq = hi * 4;
  if constexpr (OUT == 0) {
    float* Cp = (float*)C + (long)z * strC;
    #pragma unroll
    for (int i = 0; i < 4; ++i)
      #pragma unroll
      for (int r = 0; r < 4; ++r) {
        const int row = m0 + wr + i*16 + lq + r;
        if (row >= M) continue;
        #pragma unroll
        for (int j = 0; j < 4; ++j) {
          const int col = n0 + wc + j*16 + lr;
          if (col < N) Cp[(long)row * N + col] = acc[i][j][r];
        }
      }
  } else {
    u16* Cp = (u16*)C + (long)zb * strC;
    #pragma unroll
    for (int i = 0; i < 4; ++i)
      #pragma unroll
      for (int r = 0; r < 4; ++r) {
        const int row = m0 + wr + i*16 + lq + r;
        if (row >= M) continue;
        #pragma unroll
        for (int j = 0; j < 4; ++j) {
          const int col = n0 + wc + j*16 + lr;
          if (col < N) Cp[(long)row * N + col] = f2bf(acc[i][j][r] * scale);
        }
      }
  }
}

// ---------------------------------------------------------------------------
// 128x128 implicit-conv (conv2: M=64). Counted-vmcnt depth-1.
// ---------------------------------------------------------------------------
__global__ __launch_bounds__(256) void conv_glds(
    const u16* __restrict__ Wt, const u16* __restrict__ imgP,
    float* __restrict__ Cp, int M, int Cin, int Ntot, int Kc)
{
  __shared__ u16 sA[2][128 * 32];
  __shared__ u16 sB[2][128 * 32];
  const int t = threadIdx.x, lane = t & 63, wave = t >> 6;
  const int z = blockIdx.z;
  const int m0 = blockIdx.x * 128, n0 = blockIdx.y * 128;
  const int kbeg = z * Kc;

  const u16* Aptr[2]; const u16* Bptr[2]; int lofs[2];
  #pragma unroll
  for (int i = 0; i < 2; ++i) {
    const int tp = i * 256 + t;
    const int r = tp >> 2;
    const int c16 = (tp & 3) ^ ((tp >> 4) & 3);
    int ra = m0 + r; if (ra >= M) ra = M - 1;
    int pn = n0 + r; if (pn >= Ntot) pn = 0;
    const int img = pn / 784, p = pn - img * 784;
    const int py = p / 28, px = p - py * 28;
    Aptr[i] = Wt + (long)ra * (9 * Cin) + c16 * 8;
    Bptr[i] = imgP + ((long)img * 900 + (py + 1) * 30 + (px + 1)) * Cin + c16 * 8;
    lofs[i] = (i * 256 + (wave << 6)) * 8;
  }
  auto stage = [&](int buf, int kg) {
    const int tap = kg / Cin, kc = kg - tap * Cin;
    const long off = (long)((tap / 3 - 1) * 30 + (tap % 3 - 1)) * Cin + kc;
    #pragma unroll
    for (int i = 0; i < 2; ++i) {
      gld_lds16(Aptr[i] + kg, &sA[buf][lofs[i]]);
      gld_lds16(Bptr[i] + off, &sB[buf][lofs[i]]);
    }
  };

  const int wr = (wave >> 1) * 64, wc = (wave & 1) * 64;
  const int lr = lane & 15, hi = lane >> 4;
  const int csw = (hi ^ (lr >> 2)) * 8;
  f32x4v acc[4][4] = {};
  const int niter = Kc >> 5;

  stage(0, kbeg);
  for (int it = 0; it < niter; ++it) {
    const int cur = it & 1;
    if (it + 1 < niter) {
      stage(cur ^ 1, kbeg + (it + 1) * 32);
      VMCNT(4);
    } else {
      VMCNT(0);
    }
    __builtin_amdgcn_s_barrier();
    __builtin_amdgcn_sched_barrier(0);
    bf16x8 af[4], bv[4];
    #pragma unroll
    for (int i = 0; i < 4; ++i) af[i] = *(const bf16x8*)&sA[cur][(wr + i*16 + lr) * 32 + csw];
    #pragma unroll
    for (int j = 0; j < 4; ++j) bv[j] = *(const bf16x8*)&sB[cur][(wc + j*16 + lr) * 32 + csw];
    __builtin_amdgcn_s_setprio(1);
    #pragma unroll
    for (int i = 0; i < 4; ++i)
      #pragma unroll
      for (int j = 0; j < 4; ++j)
        acc[i][j] = __builtin_amdgcn_mfma_f32_16x16x32_bf16(af[i], bv[j], acc[i][j], 0, 0, 0);
    __builtin_amdgcn_s_setprio(0);
    __builtin_amdgcn_sched_barrier(0);
    __builtin_amdgcn_s_barrier();
  }

  float* Co = Cp + (long)z * M * Ntot;
  const int lq = hi * 4;
  #pragma unroll
  for (int i = 0; i < 4; ++i)
    #pragma unroll
    for (int r = 0; r < 4; ++r) {
      const int row = m0 + wr + i*16 + lq + r;
      if (row >= M) continue;
      #pragma unroll
      for (int j = 0; j < 4; ++j) {
        const int col = n0 + wc + j*16 + lr;
        if (col < Ntot) Co[(long)row * Ntot + col] = acc[i][j][r];
      }
    }
}

// ---------------------------------------------------------------------------
// Helpers
// ---------------------------------------------------------------------------
__global__ __launch_bounds__(256) void transpose_bf(
    const float* __restrict__ in, u16* __restrict__ out,
    int R, int C, long strOutZ, int ldOut, int colOff)
{
  __shared__ float tile[32][33];
  in  += (long)blockIdx.z * R * C;
  out += (long)blockIdx.z * strOutZ;
  const int c0 = blockIdx.x * 32, r0 = blockIdx.y * 32;
  const int tx = threadIdx.x & 31, ty = threadIdx.x >> 5;
  for (int i = ty; i < 32; i += 8) {
    const int r = r0 + i, c = c0 + tx;
    tile[i][tx] = (r < R && c < C) ? in[(long)r * C + c] : 0.0f;
  }
  __syncthreads();
  for (int i = ty; i < 32; i += 8) {
    const int r = r0 + tx, c = c0 + i;
    if (c < C && r < R)
      out[(long)c * ldOut + colOff + r] = f2bf(tile[tx][i]);
  }
}

__global__ __launch_bounds__(256) void convert_bf(
    const float* __restrict__ in, u16* __restrict__ out, long n8)
{
  const long i = (long)blockIdx.x * 256 + threadIdx.x;
  if (i >= n8) return;
  const float4* p = (const float4*)in + i * 2;
  const float4 a = p[0], b = p[1];
  u16 o[8] = {f2bf(a.x), f2bf(a.y), f2bf(a.z), f2bf(a.w),
              f2bf(b.x), f2bf(b.y), f2bf(b.z), f2bf(b.w)};
  ((uint4*)out)[i] = *(uint4*)o;
}

__global__ __launch_bounds__(256) void permute_w(
    const float* __restrict__ src, u16* __restrict__ dst, int M, int Cin)
{
  const long total = (long)M * 9 * Cin;
  const long idx = (long)blockIdx.x * 256 + threadIdx.x;
  if (idx >= total) return;
  const int c = (int)(idx % Cin);
  const int tap = (int)((idx / Cin) % 9);
  const int m = (int)(idx / ((long)9 * Cin));
  dst[idx] = f2bf(src[((long)m * Cin + c) * 9 + tap]);
}

__global__ __launch_bounds__(256) void zfill(u32* __restrict__ p, long n) {
  const long stride = (long)gridDim.x * 256;
  for (long i = (long)blockIdx.x * 256 + threadIdx.x; i < n; i += stride) p[i] = 0;
}

// ---------------------------------------------------------------------------
// Reduce kernels
// ---------------------------------------------------------------------------
// conv1: parts[S][1568][512] (pixel-major) -> out1P[b][900pad][512] bf16 +b1
__global__ __launch_bounds__(256) void reduce_c1_cl(
    const float* __restrict__ parts, u16* __restrict__ dst,
    const float* __restrict__ bias, int S)
{
  const long idx = (long)blockIdx.x * 256 + threadIdx.x;
  if (idx >= 1568L * 128) return;
  const int c4 = (int)(idx & 127), p = (int)(idx >> 7);
  const int c = c4 * 4;
  f32x4v sum = *(const f32x4v*)&bias[c];
  for (int s = 0; s < S; ++s)
    sum += *(const f32x4v*)&parts[((long)s * 1568 + p) * 512 + c];
  const int im = p / 784, q = p - im * 784;
  const int qpad = (q / 28 + 1) * 30 + (q % 28 + 1);
  u16 o[4] = {f2bf(sum[0]), f2bf(sum[1]), f2bf(sum[2]), f2bf(sum[3])};
  *(uint2*)&dst[((long)im * 900 + qpad) * 512 + c] = *(uint2*)o;
}

// readout: parts[(b*S+s)][1536][784] (channel-major) -> concatP[b*3+n][900pad][768]
__global__ __launch_bounds__(256) void reduceT_ro(
    const float* __restrict__ parts, u16* __restrict__ dst, int S)
{
  __shared__ float tile[32][33];
  const int b = blockIdx.z, c0 = blockIdx.x * 32, p0 = blockIdx.y * 32;
  const int tx = threadIdx.x & 31, ty = threadIdx.x >> 5;
  for (int i = ty; i < 32; i += 8) {
    const int pc = min(p0 + tx, 783);
    float s = 0;
    for (int k = 0; k < S; ++k)
      s += parts[((long)(b * S + k) * 1536 + c0 + i) * 784 + pc];
    tile[i][tx] = s;
  }
  __syncthreads();
  for (int i = ty; i < 32; i += 8) {
    const int p = p0 + i, c = c0 + tx;
    if (p < 784) {
      const int n = c >> 9, cc = c & 511;
      const int qpad = (p / 28 + 1) * 30 + (p % 28 + 1);
      dst[((long)(b * 3 + n) * 900 + qpad) * 768 + cc] = f2bf(tile[tx][i]);
    }
  }
}

// conv2: parts[S][64][1568] -> qkT[b][784][64] (+b2)
__global__ __launch_bounds__(256) void reduceT_qk(
    const float* __restrict__ parts, u16* __restrict__ dst,
    const float* __restrict__ bias, int S)
{
  __shared__ float tile[32][33];
  const int b = blockIdx.z, c0 = blockIdx.x * 32, p0 = blockIdx.y * 32;
  const int tx = threadIdx.x & 31, ty = threadIdx.x >> 5;
  for (int i = ty; i < 32; i += 8) {
    const int pc = min(p0 + tx, 783);
    const long base = (long)(c0 + i) * 1568 + b * 784 + pc;
    float s = 0;
    for (int k = 0; k < S; ++k) s += parts[(long)k * 64 * 1568 + base];
    tile[i][tx] = s;
  }
  __syncthreads();
  for (int i = ty; i < 32; i += 8) {
    const int p = p0 + i, c = c0 + tx;
    if (p < 784)
      dst[((long)b * 784 + p) * 64 + c] = f2bf(tile[tx][i] + bias[c]);
  }
}

__global__ __launch_bounds__(256) void transT_h(
    const float* __restrict__ h, u16* __restrict__ dst)
{
  __shared__ float tile[32][33];
  const int zimg = blockIdx.z, c0 = blockIdx.x * 32, p0 = blockIdx.y * 32;
  const int tx = threadIdx.x & 31, ty = threadIdx.x >> 5;
  for (int i = ty; i < 32; i += 8) {
    const int pc = min(p0 + tx, 783);
    tile[i][tx] = h[((long)zimg * 256 + c0 + i) * 784 + pc];
  }
  __syncthreads();
  for (int i = ty; i < 32; i += 8) {
    const int p = p0 + i, c = c0 + tx;
    if (p < 784) {
      const int qpad = (p / 28 + 1) * 30 + (p % 28 + 1);
      dst[((long)zimg * 900 + qpad) * 768 + 512 + c] = f2bf(tile[tx][i]);
    }
  }
}

// ---------------------------------------------------------------------------
// SINGLE-PASS in-place softmax over rows of 12544 bf16 (one block per row).
// Row held in 7 uint4 registers per thread (statically unrolled).
// ---------------------------------------------------------------------------
__global__ __launch_bounds__(256) void softmax_inplace(u16* __restrict__ buf)
{
  uint4* p4 = (uint4*)(buf + (long)blockIdx.x * 12544);
  const int t = threadIdx.x;
  __shared__ float red[4];
  uint4 v[7];
  float mx = -3.0e38f;
  #pragma unroll
  for (int q = 0; q < 7; ++q) {
    const int idx = t + q * 256;
    if (idx < 1568) {
      v[q] = p4[idx];
      const u32 w[4] = {v[q].x, v[q].y, v[q].z, v[q].w};
      #pragma unroll
      for (int e = 0; e < 4; ++e) {
        mx = fmaxf(mx, bf2f((u16)(w[e] & 0xFFFFu)));
        mx = fmaxf(mx, bf2f((u16)(w[e] >> 16)));
      }
    }
  }
  #pragma unroll
  for (int o = 32; o > 0; o >>= 1) mx = fmaxf(mx, __shfl_xor(mx, o));
  if ((t & 63) == 0) red[t >> 6] = mx;
  __syncthreads();
  mx = fmaxf(fmaxf(red[0], red[1]), fmaxf(red[2], red[3]));

  float s = 0.0f;
  #pragma unroll
  for (int q = 0; q < 7; ++q) {
    const int idx = t + q * 256;
    if (idx < 1568) {
      const u32 w[4] = {v[q].x, v[q].y, v[q].z, v[q].w};
      #pragma unroll
      for (int e = 0; e < 4; ++e) {
        s += __expf(bf2f((u16)(w[e] & 0xFFFFu)) - mx);
        s += __expf(bf2f((u16)(w[e] >> 16)) - mx);
      }
    }
  }
  #pragma unroll
  for (int o = 32; o > 0; o >>= 1) s += __shfl_xor(s, o);
  __syncthreads();
  if ((t & 63) == 0) red[t >> 6] = s;
  __syncthreads();
  const float inv = 1.0f / (red[0] + red[1] + red[2] + red[3]);

  #pragma unroll
  for (int q = 0; q < 7; ++q) {
    const int idx = t + q * 256;
    if (idx < 1568) {
      u32 w[4] = {v[q].x, v[q].y, v[q].z, v[q].w};
      #pragma unroll
      for (int e = 0; e < 4; ++e) {
        const float a = __expf(bf2f((u16)(w[e] & 0xFFFFu)) - mx) * inv;
        const float b = __expf(bf2f((u16)(w[e] >> 16)) - mx) * inv;
        w[e] = (u32)f2bf(a) | ((u32)f2bf(b) << 16);
      }
      p4[idx] = make_uint4(w[0], w[1], w[2], w[3]);
    }
  }
}

// ---------------------------------------------------------------------------
// Fused transform-reduce + gating. parts: [S][768][4704] fp32 (channel-major)
// ---------------------------------------------------------------------------
__global__ __launch_bounds__(256) void treduce_gate(
    const float* __restrict__ parts, const float* __restrict__ bt,
    const float* __restrict__ h, float* __restrict__ out, int S)
{
  const long i = (long)blockIdx.x * 256 + threadIdx.x;
  if (i >= 6L * 256 * 196) return;
  const int p4 = (int)(i % 196);
  const int rest = (int)(i / 196);
  const int cs = rest % 256, im = rest / 256;
  const long slice4 = (768L * 4704) >> 2;
  const long colBase = ((long)im * 784) >> 2;
  f32x4v F = {0,0,0,0}, U = {0,0,0,0}, NV = {0,0,0,0};
  for (int s = 0; s < S; ++s) {
    const f32x4v* P = (const f32x4v*)parts + (long)s * slice4;
    F  += P[(((long)cs        * 4704) >> 2) + colBase + p4];
    U  += P[(((long)(256 + cs) * 4704) >> 2) + colBase + p4];
    NV += P[(((long)(512 + cs) * 4704) >> 2) + colBase + p4];
  }
  const float bF = bt[cs], bU = bt[256 + cs], bN = bt[512 + cs];
  const f32x4v hv = ((const f32x4v*)h)[((long)(im * 256 + cs) * 784 >> 2) + p4];
  f32x4v o;
  #pragma unroll
  for (int q = 0; q < 4; ++q) {
    const float f = F[q] + bF, u = U[q] + bU, nv = NV[q] + bN;
    const float sf = 1.0f / (1.0f + __expf(-f));
    const float su = 1.0f / (1.0f + __expf(-u));
    const float e2 = __expf(2.0f * nv);
    const float tv = (e2 - 1.0f) / (e2 + 1.0f);
    o[q] = sf * hv[q] * (1.0f - su) + su * tv;
  }
  ((f32x4v*)out)[((long)(im * 256 + cs) * 784 >> 2) + p4] = o;
}

__global__ __launch_bounds__(256) void fill_sentinel(float* p, long n) {
  const long i = (long)blockIdx.x * 256 + threadIdx.x;
  if (i < n) p[i] = 12345.0f;
}

// ---------------------------------------------------------------------------
extern "C" void kernel_launch(void* const* d_in, const int* in_sizes, int n_in,
                              void* d_out, int out_size, void* d_ws, size_t ws_size,
                              hipStream_t stream) {
  const float* f16 = (const float*)d_in[0];
  const float* mk  = (const float*)d_in[1];
  const float* mv  = (const float*)d_in[2];
  const float* hin = (const float*)d_in[3];
  const float* w1  = (const float*)d_in[4];
  const float* b1  = (const float*)d_in[5];
  const float* w2  = (const float*)d_in[6];
  const float* b2  = (const float*)d_in[7];
  const float* wt  = (const float*)d_in[8];
  const float* bt  = (const float*)d_in[9];
  float* out = (float*)d_out;

  (void)hipFuncSetAttribute((const void*)gemmRC<0>,
                            hipFuncAttributeMaxDynamicSharedMemorySize, 73728);
  (void)hipFuncSetAttribute((const void*)gemmRC<1>,
                            hipFuncAttributeMaxDynamicSharedMemorySize, 73728);
  constexpr unsigned DSM = 73728;

  const size_t B_f16T   = 2UL*784*1024*2;
  const size_t B_w1b    = 512UL*1024*2;
  const size_t B_w2R    = 64UL*4608*2;
  const size_t B_out1P  = 2UL*900*512*2;
  const size_t B_qkT    = 2UL*784*64*2;
  const size_t B_concat = 6UL*900*768*2;
  const size_t B_wtR    = 768UL*6912*2;
  const size_t B_mkT    = 2UL*12544*64*2;
  const size_t B_logaff = 2UL*784*12544*2;
  const size_t B_mvb    = 38535168UL*2;
  auto al = [](size_t x) { return (x + 255) & ~(size_t)255; };
  auto kcFor = [](int K, int S) { return ((K + S - 1) / S + 31) & ~31; };
  auto pad8 = [](int n) { return (n + 7) & ~7; };

  const size_t phase1 = al(B_f16T) + al(B_w1b) + al(B_w2R) + al(B_out1P) + al(B_qkT);
  const size_t regionA = phase1 > al(B_concat) ? phase1 : al(B_concat);

  auto poolFor = [&](int S_ro, int S_tr) -> size_t {
    size_t p1 = 8UL*1568*512*4, p2 = 18UL*64*1568*4;
    size_t pr = (size_t)(2*S_ro)*1536*784*4, pt = (size_t)S_tr*768*4704*4;
    size_t m = p1; if (p2 > m) m = p2; if (pr > m) m = pr; if (pt > m) m = pt;
    return m;
  };
  const size_t fixed = regionA + al(B_wtR) + al(B_mkT) + al(B_logaff) + al(B_mvb);

  int S_ro = 6, S_tr = 4;   // readout grid 504, transform 444 (+4 pad)
  if (fixed + poolFor(S_ro, S_tr) > ws_size) { S_ro = 3; S_tr = 2; }
  if (fixed + poolFor(S_ro, S_tr) > ws_size) {
    fill_sentinel<<<4704, 256, 0, stream>>>(out, (long)out_size);
    return;
  }
  const int Kc_ro = kcFor(12544, S_ro);
  const int Kc_tr = kcFor(6912, S_tr);

  char* base = (char*)d_ws;
  size_t off = 0;
  auto alloc = [&](size_t bytes) -> char* { char* p = base + off; off += al(bytes); return p; };
  char* rA = alloc(regionA);
  u16* f16T   = (u16*)rA;
  u16* w1b    = (u16*)(rA + al(B_f16T));
  u16* w2R    = (u16*)(rA + al(B_f16T) + al(B_w1b));
  u16* out1P  = (u16*)(rA + al(B_f16T) + al(B_w1b) + al(B_w2R));
  u16* qkT    = (u16*)(rA + al(B_f16T) + al(B_w1b) + al(B_w2R) + al(B_out1P));
  u16* concatP = (u16*)rA;  // overlays phase-1 buffers (dead by then)
  u16*   wtR    = (u16*)alloc(B_wtR);
  u16*   mkT    = (u16*)alloc(B_mkT);
  u16*   logaff = (u16*)alloc(B_logaff);
  u16*   mvb    = (u16*)alloc(B_mvb);
  float* parts  = (float*)alloc(poolFor(S_ro, S_tr));

  // ---- zero padded conv1 image ----
  zfill<<<512, 256, 0, stream>>>((u32*)out1P, (long)(B_out1P / 4));

  // ---- operand prep ----
  convert_bf<<<256, 256, 0, stream>>>(w1, w1b, 65536);
  permute_w<<<1152, 256, 0, stream>>>(w2, w2R, 64, 512);
  permute_w<<<20736, 256, 0, stream>>>(wt, wtR, 768, 768);
  transpose_bf<<<dim3(25, 32, 2), 256, 0, stream>>>(f16, f16T, 1024, 784, 784L*1024, 1024, 0);
  transpose_bf<<<dim3(392, 2, 2), 256, 0, stream>>>(mk, mkT, 64, 12544, 12544L*64, 64, 0);
  convert_bf<<<18816, 256, 0, stream>>>(mv, mvb, 4816896);

  // ---- conv1 (1x1): A=f16T[1568][1024], B=w1b[512][1024], S=8, XCD-chunked ----
  {
    const int nwg = 7 * 4 * 8;
    gemmRC<0><<<pad8(nwg), 512, DSM, stream>>>(
        f16T, w1b, parts, 1568, 512, 128, 1024, 8, 0, 0, 1568L*512, 0, 7, 4, nwg);
  }
  reduce_c1_cl<<<784, 256, 0, stream>>>(parts, out1P, b1, 8);

  // ---- conv2 (3x3 implicit 128-tile): M=64, Cin=512, Ntot=1568, S=18 ----
  conv_glds<<<dim3(1, 13, 18), 256, 0, stream>>>(w2R, out1P, parts, 64, 512, 1568, 256);
  reduceT_qk<<<dim3(2, 25, 2), 256, 0, stream>>>(parts, qkT, b2, 18);

  // ---- logits: M=784, N=12544, K=64 -> bf16, scale 1/8 ----
  gemm_glds<64, 1><<<dim3(7, 98, 2), 256, 0, stream>>>(
      qkT, mkT, logaff, 784, 12544, 64, 64, 1,
      784L*64, 12544L*64, 784L*12544, 0.125f);

  // ---- softmax over memory axis (single-pass, reg-resident) ----
  softmax_inplace<<<1568, 256, 0, stream>>>(logaff);

  // ---- zero concat image, fill h channels ----
  zfill<<<2048, 256, 0, stream>>>((u32*)concatP, (long)(B_concat / 4));
  transT_h<<<dim3(8, 25, 6), 256, 0, stream>>>(hin, concatP);

  // ---- readout: A=mvb[1536][12544], B=logaff[784][12544], XCD-chunked ----
  {
    const int nwg = 6 * 7 * 2 * S_ro;
    gemmRC<0><<<pad8(nwg), 512, DSM, stream>>>(
        mvb, logaff, parts, 1536, 784, Kc_ro, 12544, S_ro,
        1536L*12544, 784L*12544, 1536L*784, 0, 6, 7, nwg);
  }
  reduceT_ro<<<dim3(48, 25, 2), 256, 0, stream>>>(parts, concatP, S_ro);

  // ---- transform conv: A=wtR[768][9*768], B=concatP pixels, XCD-chunked ----
  {
    const int nwg = 3 * 37 * S_tr;
    gemmRC<1><<<pad8(nwg), 512, DSM, stream>>>(
        wtR, concatP, parts, 768, 4704, Kc_tr, 6912, S_tr,
        0, 0, 768L*4704, 768, 3, 37, nwg);
  }

  // ---- fused reduce + gating -> d_out ----
  treduce_gate<<<1176, 256, 0, stream>>>(parts, bt, hin, out, S_tr);
}